// Round 3
// baseline (6059.097 us; speedup 1.0000x reference)
//
#include <hip/hip_runtime.h>

// SignedGCN on MI355X. Pull-style aggregation via on-device CSR build.
// R3: ILP restructure — 4 rows/wave in linears (4 indep load streams, 4x LDS reuse),
//     widened gathers in aggregation (float2/float4 per lane, unroll-4).

__global__ void count_kernel(const int* __restrict__ pei, const int* __restrict__ nei,
                             int* __restrict__ cnt_p, int* __restrict__ cnt_n, int e) {
  int i = blockIdx.x * blockDim.x + threadIdx.x;
  if (i < e) {
    atomicAdd(&cnt_p[pei[e + i]], 1);
  } else if (i < 2 * e) {
    atomicAdd(&cnt_n[nei[e + (i - e)]], 1);
  }
}

__global__ void alloc_kernel(const int* __restrict__ cnt_p, const int* __restrict__ cnt_n,
                             int* __restrict__ off_p, int* __restrict__ off_n,
                             int* __restrict__ cur_p, int* __restrict__ cur_n,
                             int* __restrict__ tots, int n) {
  int v = blockIdx.x * blockDim.x + threadIdx.x;
  int lane = threadIdx.x & 63;
  int vp = (v < n) ? cnt_p[v] : 0;
  int vn = (v < n) ? cnt_n[v] : 0;
  int sp = vp, sn = vn;
  #pragma unroll
  for (int d = 1; d < 64; d <<= 1) {
    int tp = __shfl_up(sp, d);
    int tn = __shfl_up(sn, d);
    if (lane >= d) { sp += tp; sn += tn; }
  }
  int basep = 0, basen = 0;
  if (lane == 63) {
    basep = atomicAdd(&tots[0], sp);
    basen = atomicAdd(&tots[1], sn);
  }
  basep = __shfl(basep, 63);
  basen = __shfl(basen, 63);
  if (v < n) {
    int op = basep + sp - vp;
    int on = basen + sn - vn;
    off_p[v] = op; cur_p[v] = op;
    off_n[v] = on; cur_n[v] = on;
  }
}

__global__ void fill_kernel(const int* __restrict__ pei, const int* __restrict__ nei,
                            int* __restrict__ cur_p, int* __restrict__ cur_n,
                            int* __restrict__ list_p, int* __restrict__ list_n, int e) {
  int i = blockIdx.x * blockDim.x + threadIdx.x;
  if (i < e) {
    int dst = pei[e + i];
    int p = atomicAdd(&cur_p[dst], 1);
    list_p[p] = pei[i];
  } else if (i < 2 * e) {
    int j = i - e;
    int dst = nei[e + j];
    int p = atomicAdd(&cur_n[dst], 1);
    list_n[p] = nei[j];
  }
}

// Layer-1 aggregation: wave handles 4 nodes for one graph; 16-lane group per node,
// float4 per lane (256 B coalesced gather per group, 4 concurrent gathers per wave).
__global__ void agg1_kernel(const float* __restrict__ x,
                            const int* __restrict__ off_p, const int* __restrict__ cnt_p, const int* __restrict__ list_p,
                            const int* __restrict__ off_n, const int* __restrict__ cnt_n, const int* __restrict__ list_n,
                            float* __restrict__ Mp, float* __restrict__ Mn, int n) {
  int wid = (blockIdx.x * blockDim.x + threadIdx.x) >> 6;
  int lane = threadIdx.x & 63;
  int grp = lane >> 4, sl = lane & 15;
  int g = wid & 1;
  int v = (wid >> 1) * 4 + grp;
  const int* off = g ? off_n : off_p;
  const int* cnt = g ? cnt_n : cnt_p;
  const int* lst = g ? list_n : list_p;
  float* M = g ? Mn : Mp;
  bool valid = v < n;
  int vc = valid ? v : 0;
  int d = valid ? cnt[vc] : 0;
  int o = valid ? off[vc] : 0;
  float4 acc = make_float4(0.f, 0.f, 0.f, 0.f);
  int i = 0;
  for (; i + 4 <= d; i += 4) {
    int s0 = lst[o + i], s1 = lst[o + i + 1], s2 = lst[o + i + 2], s3 = lst[o + i + 3];
    float4 r0 = *((const float4*)(x + (size_t)s0 * 64) + sl);
    float4 r1 = *((const float4*)(x + (size_t)s1 * 64) + sl);
    float4 r2 = *((const float4*)(x + (size_t)s2 * 64) + sl);
    float4 r3 = *((const float4*)(x + (size_t)s3 * 64) + sl);
    acc.x += r0.x + r1.x + r2.x + r3.x;
    acc.y += r0.y + r1.y + r2.y + r3.y;
    acc.z += r0.z + r1.z + r2.z + r3.z;
    acc.w += r0.w + r1.w + r2.w + r3.w;
  }
  for (; i < d; ++i) {
    int s = lst[o + i];
    float4 r = *((const float4*)(x + (size_t)s * 64) + sl);
    acc.x += r.x; acc.y += r.y; acc.z += r.z; acc.w += r.w;
  }
  if (valid) {
    float inv = 1.f / (float)(d > 0 ? d : 1);
    float4 res = make_float4(acc.x * inv, acc.y * inv, acc.z * inv, acc.w * inv);
    *(float4*)(M + (size_t)v * 64 + sl * 4) = res;
  }
}

// Layer-2 aggregation over z (128 ch): wave per (node, graph), float2 per lane
// (512 B coalesced gather per row, unroll-4 = 4 outstanding gathers).
__global__ void agg2_kernel(const float* __restrict__ z,
                            const int* __restrict__ off_p, const int* __restrict__ cnt_p, const int* __restrict__ list_p,
                            const int* __restrict__ off_n, const int* __restrict__ cnt_n, const int* __restrict__ list_n,
                            float* __restrict__ Ap, float* __restrict__ An, int n) {
  int wid = (blockIdx.x * blockDim.x + threadIdx.x) >> 6;
  int lane = threadIdx.x & 63;
  int v = wid >> 1;
  if (v >= n) return;
  int g = wid & 1;
  const int* off = g ? off_n : off_p;
  const int* cnt = g ? cnt_n : cnt_p;
  const int* lst = g ? list_n : list_p;
  float* A = g ? An : Ap;
  int d = cnt[v], o = off[v];
  int c = lane * 2;
  float2 acc = make_float2(0.f, 0.f);
  int i = 0;
  for (; i + 4 <= d; i += 4) {
    int s0 = lst[o + i], s1 = lst[o + i + 1], s2 = lst[o + i + 2], s3 = lst[o + i + 3];
    float2 r0 = *(const float2*)(z + (size_t)s0 * 128 + c);
    float2 r1 = *(const float2*)(z + (size_t)s1 * 128 + c);
    float2 r2 = *(const float2*)(z + (size_t)s2 * 128 + c);
    float2 r3 = *(const float2*)(z + (size_t)s3 * 128 + c);
    acc.x += r0.x + r1.x + r2.x + r3.x;
    acc.y += r0.y + r1.y + r2.y + r3.y;
  }
  for (; i < d; ++i) {
    int s = lst[o + i];
    float2 r = *(const float2*)(z + (size_t)s * 128 + c);
    acc.x += r.x; acc.y += r.y;
  }
  float inv = 1.f / (float)(d > 0 ? d : 1);
  *(float2*)(A + (size_t)v * 128 + c) = make_float2(acc.x * inv, acc.y * inv);
}

// z[:, half*64 + jj] = relu([M, x] @ W.T + b). 4 rows per wave-iteration:
// 4 independent broadcast-load streams, each LDS W-read reused by 4 FMAs.
__global__ __launch_bounds__(512) void lin1_kernel(
    const float* __restrict__ x, const float* __restrict__ Mp, const float* __restrict__ Mn,
    const float* __restrict__ Wp1, const float* __restrict__ bp1,
    const float* __restrict__ Wn1, const float* __restrict__ bn1,
    float* __restrict__ z, int n) {
  __shared__ float Wt[128 * 64];  // Wt[k][j] = W[j][k], 32 KiB
  int half = blockIdx.y;
  const float* W  = half ? Wn1 : Wp1;
  const float* bb = half ? bn1 : bp1;
  const float* M  = half ? Mn : Mp;
  for (int f = threadIdx.x; f < 128 * 64; f += 512) {
    int k = f >> 6, j = f & 63;
    Wt[f] = W[j * 128 + k];
  }
  __syncthreads();
  int lane = threadIdx.x & 63;
  float bias = bb[lane];
  int wpb = 512 >> 6;  // 8 waves/block
  int gw = blockIdx.x * wpb + (threadIdx.x >> 6);
  int wstride = gridDim.x * wpb;
  for (int v0 = gw * 4; v0 < n; v0 += wstride * 4) {
    const float4* mrow[4];
    const float4* xrow[4];
    #pragma unroll
    for (int r = 0; r < 4; ++r) {
      int vr = v0 + r; if (vr >= n) vr = n - 1;
      mrow[r] = (const float4*)(M + (size_t)vr * 64);
      xrow[r] = (const float4*)(x + (size_t)vr * 64);
    }
    float acc[4];
    #pragma unroll
    for (int r = 0; r < 4; ++r) acc[r] = bias;
    #pragma unroll
    for (int k4 = 0; k4 < 16; ++k4) {
      float4 a[4];
      #pragma unroll
      for (int r = 0; r < 4; ++r) a[r] = mrow[r][k4];
      #pragma unroll
      for (int c = 0; c < 4; ++c) {
        float w = Wt[(k4 * 4 + c) * 64 + lane];
        #pragma unroll
        for (int r = 0; r < 4; ++r)
          acc[r] = fmaf(((const float*)&a[r])[c], w, acc[r]);
      }
    }
    #pragma unroll
    for (int k4 = 0; k4 < 16; ++k4) {
      float4 a[4];
      #pragma unroll
      for (int r = 0; r < 4; ++r) a[r] = xrow[r][k4];
      #pragma unroll
      for (int c = 0; c < 4; ++c) {
        float w = Wt[(64 + k4 * 4 + c) * 64 + lane];
        #pragma unroll
        for (int r = 0; r < 4; ++r)
          acc[r] = fmaf(((const float*)&a[r])[c], w, acc[r]);
      }
    }
    #pragma unroll
    for (int r = 0; r < 4; ++r) {
      int vr = v0 + r;
      if (vr < n) z[(size_t)vr * 128 + half * 64 + lane] = fmaxf(acc[r], 0.f);
    }
  }
}

// out[:, half*64+jj] = relu([A1, A2, Zr] @ W.T + b). Same 4-row structure, K=192.
__global__ __launch_bounds__(512) void lin2_kernel(
    const float* __restrict__ z, const float* __restrict__ Ap, const float* __restrict__ An,
    const float* __restrict__ Wp2, const float* __restrict__ bp2,
    const float* __restrict__ Wn2, const float* __restrict__ bn2,
    float* __restrict__ out, int n) {
  __shared__ float Wt[192 * 64];  // 48 KiB
  int half = blockIdx.y;
  const float* W  = half ? Wn2 : Wp2;
  const float* bb = half ? bn2 : bp2;
  for (int f = threadIdx.x; f < 192 * 64; f += 512) {
    int k = f >> 6, j = f & 63;
    Wt[f] = W[j * 192 + k];
  }
  __syncthreads();
  int lane = threadIdx.x & 63;
  float bias = bb[lane];
  int wpb = 512 >> 6;
  int gw = blockIdx.x * wpb + (threadIdx.x >> 6);
  int wstride = gridDim.x * wpb;
  size_t a1off = half ? 64 : 0;   // Ap column offset
  size_t a2off = half ? 0 : 64;   // An column offset
  size_t zoff  = half ? 64 : 0;   // z  column offset
  for (int v0 = gw * 4; v0 < n; v0 += wstride * 4) {
    const float4* a1row[4];
    const float4* a2row[4];
    const float4* zrow[4];
    #pragma unroll
    for (int r = 0; r < 4; ++r) {
      int vr = v0 + r; if (vr >= n) vr = n - 1;
      a1row[r] = (const float4*)(Ap + (size_t)vr * 128 + a1off);
      a2row[r] = (const float4*)(An + (size_t)vr * 128 + a2off);
      zrow[r]  = (const float4*)(z  + (size_t)vr * 128 + zoff);
    }
    float acc[4];
    #pragma unroll
    for (int r = 0; r < 4; ++r) acc[r] = bias;
    #pragma unroll
    for (int k4 = 0; k4 < 16; ++k4) {
      float4 a[4];
      #pragma unroll
      for (int r = 0; r < 4; ++r) a[r] = a1row[r][k4];
      #pragma unroll
      for (int c = 0; c < 4; ++c) {
        float w = Wt[(k4 * 4 + c) * 64 + lane];
        #pragma unroll
        for (int r = 0; r < 4; ++r)
          acc[r] = fmaf(((const float*)&a[r])[c], w, acc[r]);
      }
    }
    #pragma unroll
    for (int k4 = 0; k4 < 16; ++k4) {
      float4 a[4];
      #pragma unroll
      for (int r = 0; r < 4; ++r) a[r] = a2row[r][k4];
      #pragma unroll
      for (int c = 0; c < 4; ++c) {
        float w = Wt[(64 + k4 * 4 + c) * 64 + lane];
        #pragma unroll
        for (int r = 0; r < 4; ++r)
          acc[r] = fmaf(((const float*)&a[r])[c], w, acc[r]);
      }
    }
    #pragma unroll
    for (int k4 = 0; k4 < 16; ++k4) {
      float4 a[4];
      #pragma unroll
      for (int r = 0; r < 4; ++r) a[r] = zrow[r][k4];
      #pragma unroll
      for (int c = 0; c < 4; ++c) {
        float w = Wt[(128 + k4 * 4 + c) * 64 + lane];
        #pragma unroll
        for (int r = 0; r < 4; ++r)
          acc[r] = fmaf(((const float*)&a[r])[c], w, acc[r]);
      }
    }
    #pragma unroll
    for (int r = 0; r < 4; ++r) {
      int vr = v0 + r;
      if (vr < n) out[(size_t)vr * 128 + half * 64 + lane] = fmaxf(acc[r], 0.f);
    }
  }
}

extern "C" void kernel_launch(void* const* d_in, const int* in_sizes, int n_in,
                              void* d_out, int out_size, void* d_ws, size_t ws_size,
                              hipStream_t stream) {
  const float* x   = (const float*)d_in[0];
  const int*   pei = (const int*)d_in[1];
  const int*   nei = (const int*)d_in[2];
  const float* Wp1 = (const float*)d_in[3];
  const float* bp1 = (const float*)d_in[4];
  const float* Wn1 = (const float*)d_in[5];
  const float* bn1 = (const float*)d_in[6];
  const float* Wp2 = (const float*)d_in[7];
  const float* bp2 = (const float*)d_in[8];
  const float* Wn2 = (const float*)d_in[9];
  const float* bn2 = (const float*)d_in[10];
  float* out = (float*)d_out;

  const int n = in_sizes[0] / 64;   // 100000
  const int e = in_sizes[1] / 2;    // 1600000

  char* w = (char*)d_ws;
  size_t off = 0;
  auto take = [&](size_t bytes) -> void* {
    void* p = (void*)(w + off);
    off += (bytes + 255) & ~(size_t)255;
    return p;
  };
  int* cnt_p  = (int*)take((size_t)n * 4);
  int* cnt_n  = (int*)take((size_t)n * 4);
  int* tots   = (int*)take(8);
  int* off_p  = (int*)take((size_t)n * 4);
  int* off_n  = (int*)take((size_t)n * 4);
  int* cur_p  = (int*)take((size_t)n * 4);
  int* cur_n  = (int*)take((size_t)n * 4);
  int* list_p = (int*)take((size_t)e * 4);
  int* list_n = (int*)take((size_t)e * 4);
  float* Mp = (float*)take((size_t)n * 64 * 4);   // n*64*4 is 256B-multiple => Mn contiguous
  float* Mn = (float*)take((size_t)n * 64 * 4);
  float* z  = (float*)take((size_t)n * 128 * 4);
  float* An = (float*)take((size_t)n * 128 * 4);
  float* Ap = Mp;  // alias: Mp/Mn dead after lin1; Ap spans both (n*128 floats)

  hipMemsetAsync(cnt_p, 0, (size_t)n * 4, stream);
  hipMemsetAsync(cnt_n, 0, (size_t)n * 4, stream);
  hipMemsetAsync(tots, 0, 8, stream);

  int blkE = (2 * e + 255) / 256;
  count_kernel<<<blkE, 256, 0, stream>>>(pei, nei, cnt_p, cnt_n, e);
  alloc_kernel<<<(n + 255) / 256, 256, 0, stream>>>(cnt_p, cnt_n, off_p, off_n, cur_p, cur_n, tots, n);
  fill_kernel<<<blkE, 256, 0, stream>>>(pei, nei, cur_p, cur_n, list_p, list_n, e);

  // layer 1
  int agg1_waves = ((n + 3) / 4) * 2;
  agg1_kernel<<<(agg1_waves * 64 + 255) / 256, 256, 0, stream>>>(
      x, off_p, cnt_p, list_p, off_n, cnt_n, list_n, Mp, Mn, n);
  dim3 g1(512, 2);
  lin1_kernel<<<g1, 512, 0, stream>>>(x, Mp, Mn, Wp1, bp1, Wn1, bn1, z, n);

  // layer 2
  int agg2_waves = 2 * n;
  agg2_kernel<<<(agg2_waves * 64 + 255) / 256, 256, 0, stream>>>(
      z, off_p, cnt_p, list_p, off_n, cnt_n, list_n, Ap, An, n);
  lin2_kernel<<<g1, 512, 0, stream>>>(z, Ap, An, Wp2, bp2, Wn2, bn2, out, n);
}

// Round 4
// 3713.998 us; speedup vs baseline: 1.6314x; 1.6314x over previous
//
#include <hip/hip_runtime.h>

// SignedGCN on MI355X. Pull-style aggregation via on-device CSR build.
// R4: revert aggs/CSR to R2 (proven). Linears: R2 mapping (wave=row, lane=outcol)
// + 4 independent named-scalar accumulators (break dependent FMA chain)
// + 2 rows/wave (halve LDS W-read traffic). NO address-taken arrays (R3 lesson).

__global__ void count_kernel(const int* __restrict__ pei, const int* __restrict__ nei,
                             int* __restrict__ cnt_p, int* __restrict__ cnt_n, int e) {
  int i = blockIdx.x * blockDim.x + threadIdx.x;
  if (i < e) {
    atomicAdd(&cnt_p[pei[e + i]], 1);
  } else if (i < 2 * e) {
    atomicAdd(&cnt_n[nei[e + (i - e)]], 1);
  }
}

__global__ void alloc_kernel(const int* __restrict__ cnt_p, const int* __restrict__ cnt_n,
                             int* __restrict__ off_p, int* __restrict__ off_n,
                             int* __restrict__ cur_p, int* __restrict__ cur_n,
                             int* __restrict__ tots, int n) {
  int v = blockIdx.x * blockDim.x + threadIdx.x;
  int lane = threadIdx.x & 63;
  int vp = (v < n) ? cnt_p[v] : 0;
  int vn = (v < n) ? cnt_n[v] : 0;
  int sp = vp, sn = vn;
  #pragma unroll
  for (int d = 1; d < 64; d <<= 1) {
    int tp = __shfl_up(sp, d);
    int tn = __shfl_up(sn, d);
    if (lane >= d) { sp += tp; sn += tn; }
  }
  int basep = 0, basen = 0;
  if (lane == 63) {
    basep = atomicAdd(&tots[0], sp);
    basen = atomicAdd(&tots[1], sn);
  }
  basep = __shfl(basep, 63);
  basen = __shfl(basen, 63);
  if (v < n) {
    int op = basep + sp - vp;
    int on = basen + sn - vn;
    off_p[v] = op; cur_p[v] = op;
    off_n[v] = on; cur_n[v] = on;
  }
}

__global__ void fill_kernel(const int* __restrict__ pei, const int* __restrict__ nei,
                            int* __restrict__ cur_p, int* __restrict__ cur_n,
                            int* __restrict__ list_p, int* __restrict__ list_n, int e) {
  int i = blockIdx.x * blockDim.x + threadIdx.x;
  if (i < e) {
    int dst = pei[e + i];
    int p = atomicAdd(&cur_p[dst], 1);
    list_p[p] = pei[i];
  } else if (i < 2 * e) {
    int j = i - e;
    int dst = nei[e + j];
    int p = atomicAdd(&cur_n[dst], 1);
    list_n[p] = nei[j];
  }
}

// Layer-1 aggregation: wave per (node, graph); lane = channel (64 ch). [R2 version]
__global__ void agg1_kernel(const float* __restrict__ x,
                            const int* __restrict__ off_p, const int* __restrict__ cnt_p, const int* __restrict__ list_p,
                            const int* __restrict__ off_n, const int* __restrict__ cnt_n, const int* __restrict__ list_n,
                            float* __restrict__ Mp, float* __restrict__ Mn, int n) {
  int wid = (blockIdx.x * blockDim.x + threadIdx.x) >> 6;
  int lane = threadIdx.x & 63;
  int v = wid >> 1;
  if (v >= n) return;
  int g = wid & 1;
  const int* off = g ? off_n : off_p;
  const int* cnt = g ? cnt_n : cnt_p;
  const int* lst = g ? list_n : list_p;
  float* M = g ? Mn : Mp;
  int d = cnt[v], o = off[v];
  float acc = 0.f;
  int i = 0;
  for (; i + 4 <= d; i += 4) {
    int s0 = lst[o + i], s1 = lst[o + i + 1], s2 = lst[o + i + 2], s3 = lst[o + i + 3];
    acc += x[(size_t)s0 * 64 + lane];
    acc += x[(size_t)s1 * 64 + lane];
    acc += x[(size_t)s2 * 64 + lane];
    acc += x[(size_t)s3 * 64 + lane];
  }
  for (; i < d; ++i) acc += x[(size_t)lst[o + i] * 64 + lane];
  M[(size_t)v * 64 + lane] = acc / (float)(d > 0 ? d : 1);
}

// Layer-2 aggregation over z (128 ch): wave per (node, graph, half64). [R2 version]
__global__ void agg2_kernel(const float* __restrict__ z,
                            const int* __restrict__ off_p, const int* __restrict__ cnt_p, const int* __restrict__ list_p,
                            const int* __restrict__ off_n, const int* __restrict__ cnt_n, const int* __restrict__ list_n,
                            float* __restrict__ Ap, float* __restrict__ An, int n) {
  int wid = (blockIdx.x * blockDim.x + threadIdx.x) >> 6;
  int lane = threadIdx.x & 63;
  int v = wid >> 2;
  if (v >= n) return;
  int g = (wid >> 1) & 1;
  int h = wid & 1;
  const int* off = g ? off_n : off_p;
  const int* cnt = g ? cnt_n : cnt_p;
  const int* lst = g ? list_n : list_p;
  float* A = g ? An : Ap;
  int d = cnt[v], o = off[v];
  int c = h * 64 + lane;
  float acc = 0.f;
  int i = 0;
  for (; i + 4 <= d; i += 4) {
    int s0 = lst[o + i], s1 = lst[o + i + 1], s2 = lst[o + i + 2], s3 = lst[o + i + 3];
    acc += z[(size_t)s0 * 128 + c];
    acc += z[(size_t)s1 * 128 + c];
    acc += z[(size_t)s2 * 128 + c];
    acc += z[(size_t)s3 * 128 + c];
  }
  for (; i < d; ++i) acc += z[(size_t)lst[o + i] * 128 + c];
  A[(size_t)v * 128 + c] = acc / (float)(d > 0 ? d : 1);
}

// z[:, half*64 + lane] = relu([M, x] @ W.T + b). Wave = 2 rows, lane = out col.
// 4 independent accumulators per row (named scalars) break the dependent FMA chain.
__global__ __launch_bounds__(1024) void lin1_kernel(
    const float* __restrict__ x, const float* __restrict__ Mp, const float* __restrict__ Mn,
    const float* __restrict__ Wp1, const float* __restrict__ bp1,
    const float* __restrict__ Wn1, const float* __restrict__ bn1,
    float* __restrict__ z, int n) {
  __shared__ float Wt[128 * 64];  // Wt[k][j] = W[j][k], 32 KiB
  int half = blockIdx.y;
  const float* W  = half ? Wn1 : Wp1;
  const float* bb = half ? bn1 : bp1;
  const float* M  = half ? Mn : Mp;
  for (int f = threadIdx.x; f < 128 * 64; f += 1024) {
    int k = f >> 6, j = f & 63;
    Wt[f] = W[j * 128 + k];
  }
  __syncthreads();
  int lane = threadIdx.x & 63;
  float bias = bb[lane];
  int gw = blockIdx.x * 16 + (threadIdx.x >> 6);
  int wstride = gridDim.x * 16;
  for (int v0 = gw * 2; v0 < n; v0 += wstride * 2) {
    int v1 = (v0 + 1 < n) ? v0 + 1 : v0;
    const float4* m0 = (const float4*)(M + (size_t)v0 * 64);
    const float4* m1 = (const float4*)(M + (size_t)v1 * 64);
    const float4* x0 = (const float4*)(x + (size_t)v0 * 64);
    const float4* x1 = (const float4*)(x + (size_t)v1 * 64);
    float a0 = bias, a1 = 0.f, a2 = 0.f, a3 = 0.f;
    float b0 = bias, b1 = 0.f, b2 = 0.f, b3 = 0.f;
    #pragma unroll
    for (int k4 = 0; k4 < 16; ++k4) {
      float4 u0 = m0[k4];
      float4 u1 = m1[k4];
      float w0 = Wt[(k4 * 4 + 0) * 64 + lane];
      float w1 = Wt[(k4 * 4 + 1) * 64 + lane];
      float w2 = Wt[(k4 * 4 + 2) * 64 + lane];
      float w3 = Wt[(k4 * 4 + 3) * 64 + lane];
      a0 = fmaf(u0.x, w0, a0); a1 = fmaf(u0.y, w1, a1);
      a2 = fmaf(u0.z, w2, a2); a3 = fmaf(u0.w, w3, a3);
      b0 = fmaf(u1.x, w0, b0); b1 = fmaf(u1.y, w1, b1);
      b2 = fmaf(u1.z, w2, b2); b3 = fmaf(u1.w, w3, b3);
    }
    #pragma unroll
    for (int k4 = 0; k4 < 16; ++k4) {
      float4 u0 = x0[k4];
      float4 u1 = x1[k4];
      float w0 = Wt[(64 + k4 * 4 + 0) * 64 + lane];
      float w1 = Wt[(64 + k4 * 4 + 1) * 64 + lane];
      float w2 = Wt[(64 + k4 * 4 + 2) * 64 + lane];
      float w3 = Wt[(64 + k4 * 4 + 3) * 64 + lane];
      a0 = fmaf(u0.x, w0, a0); a1 = fmaf(u0.y, w1, a1);
      a2 = fmaf(u0.z, w2, a2); a3 = fmaf(u0.w, w3, a3);
      b0 = fmaf(u1.x, w0, b0); b1 = fmaf(u1.y, w1, b1);
      b2 = fmaf(u1.z, w2, b2); b3 = fmaf(u1.w, w3, b3);
    }
    float r0 = (a0 + a1) + (a2 + a3);
    float r1 = (b0 + b1) + (b2 + b3);
    z[(size_t)v0 * 128 + half * 64 + lane] = fmaxf(r0, 0.f);
    if (v0 + 1 < n)
      z[(size_t)(v0 + 1) * 128 + half * 64 + lane] = fmaxf(r1, 0.f);
  }
}

// out[:, half*64+lane] = relu([A1, A2, Zr] @ W.T + b). Same structure, K=192.
__global__ __launch_bounds__(1024) void lin2_kernel(
    const float* __restrict__ z, const float* __restrict__ Ap, const float* __restrict__ An,
    const float* __restrict__ Wp2, const float* __restrict__ bp2,
    const float* __restrict__ Wn2, const float* __restrict__ bn2,
    float* __restrict__ out, int n) {
  __shared__ float Wt[192 * 64];  // 48 KiB
  int half = blockIdx.y;
  const float* W  = half ? Wn2 : Wp2;
  const float* bb = half ? bn2 : bp2;
  for (int f = threadIdx.x; f < 192 * 64; f += 1024) {
    int k = f >> 6, j = f & 63;
    Wt[f] = W[j * 192 + k];
  }
  __syncthreads();
  int lane = threadIdx.x & 63;
  float bias = bb[lane];
  int gw = blockIdx.x * 16 + (threadIdx.x >> 6);
  int wstride = gridDim.x * 16;
  size_t a1off = half ? 64 : 0;   // Ap column offset
  size_t a2off = half ? 0 : 64;   // An column offset
  size_t zoff  = half ? 64 : 0;   // z  column offset
  for (int v0 = gw * 2; v0 < n; v0 += wstride * 2) {
    int v1 = (v0 + 1 < n) ? v0 + 1 : v0;
    const float4* p10 = (const float4*)(Ap + (size_t)v0 * 128 + a1off);
    const float4* p11 = (const float4*)(Ap + (size_t)v1 * 128 + a1off);
    const float4* p20 = (const float4*)(An + (size_t)v0 * 128 + a2off);
    const float4* p21 = (const float4*)(An + (size_t)v1 * 128 + a2off);
    const float4* p30 = (const float4*)(z  + (size_t)v0 * 128 + zoff);
    const float4* p31 = (const float4*)(z  + (size_t)v1 * 128 + zoff);
    float a0 = bias, a1 = 0.f, a2 = 0.f, a3 = 0.f;
    float b0 = bias, b1 = 0.f, b2 = 0.f, b3 = 0.f;
    #pragma unroll
    for (int k4 = 0; k4 < 16; ++k4) {
      float4 u0 = p10[k4];
      float4 u1 = p11[k4];
      float w0 = Wt[(k4 * 4 + 0) * 64 + lane];
      float w1 = Wt[(k4 * 4 + 1) * 64 + lane];
      float w2 = Wt[(k4 * 4 + 2) * 64 + lane];
      float w3 = Wt[(k4 * 4 + 3) * 64 + lane];
      a0 = fmaf(u0.x, w0, a0); a1 = fmaf(u0.y, w1, a1);
      a2 = fmaf(u0.z, w2, a2); a3 = fmaf(u0.w, w3, a3);
      b0 = fmaf(u1.x, w0, b0); b1 = fmaf(u1.y, w1, b1);
      b2 = fmaf(u1.z, w2, b2); b3 = fmaf(u1.w, w3, b3);
    }
    #pragma unroll
    for (int k4 = 0; k4 < 16; ++k4) {
      float4 u0 = p20[k4];
      float4 u1 = p21[k4];
      float w0 = Wt[(64 + k4 * 4 + 0) * 64 + lane];
      float w1 = Wt[(64 + k4 * 4 + 1) * 64 + lane];
      float w2 = Wt[(64 + k4 * 4 + 2) * 64 + lane];
      float w3 = Wt[(64 + k4 * 4 + 3) * 64 + lane];
      a0 = fmaf(u0.x, w0, a0); a1 = fmaf(u0.y, w1, a1);
      a2 = fmaf(u0.z, w2, a2); a3 = fmaf(u0.w, w3, a3);
      b0 = fmaf(u1.x, w0, b0); b1 = fmaf(u1.y, w1, b1);
      b2 = fmaf(u1.z, w2, b2); b3 = fmaf(u1.w, w3, b3);
    }
    #pragma unroll
    for (int k4 = 0; k4 < 16; ++k4) {
      float4 u0 = p30[k4];
      float4 u1 = p31[k4];
      float w0 = Wt[(128 + k4 * 4 + 0) * 64 + lane];
      float w1 = Wt[(128 + k4 * 4 + 1) * 64 + lane];
      float w2 = Wt[(128 + k4 * 4 + 2) * 64 + lane];
      float w3 = Wt[(128 + k4 * 4 + 3) * 64 + lane];
      a0 = fmaf(u0.x, w0, a0); a1 = fmaf(u0.y, w1, a1);
      a2 = fmaf(u0.z, w2, a2); a3 = fmaf(u0.w, w3, a3);
      b0 = fmaf(u1.x, w0, b0); b1 = fmaf(u1.y, w1, b1);
      b2 = fmaf(u1.z, w2, b2); b3 = fmaf(u1.w, w3, b3);
    }
    float r0 = (a0 + a1) + (a2 + a3);
    float r1 = (b0 + b1) + (b2 + b3);
    out[(size_t)v0 * 128 + half * 64 + lane] = fmaxf(r0, 0.f);
    if (v0 + 1 < n)
      out[(size_t)(v0 + 1) * 128 + half * 64 + lane] = fmaxf(r1, 0.f);
  }
}

extern "C" void kernel_launch(void* const* d_in, const int* in_sizes, int n_in,
                              void* d_out, int out_size, void* d_ws, size_t ws_size,
                              hipStream_t stream) {
  const float* x   = (const float*)d_in[0];
  const int*   pei = (const int*)d_in[1];
  const int*   nei = (const int*)d_in[2];
  const float* Wp1 = (const float*)d_in[3];
  const float* bp1 = (const float*)d_in[4];
  const float* Wn1 = (const float*)d_in[5];
  const float* bn1 = (const float*)d_in[6];
  const float* Wp2 = (const float*)d_in[7];
  const float* bp2 = (const float*)d_in[8];
  const float* Wn2 = (const float*)d_in[9];
  const float* bn2 = (const float*)d_in[10];
  float* out = (float*)d_out;

  const int n = in_sizes[0] / 64;   // 100000
  const int e = in_sizes[1] / 2;    // 1600000

  char* w = (char*)d_ws;
  size_t off = 0;
  auto take = [&](size_t bytes) -> void* {
    void* p = (void*)(w + off);
    off += (bytes + 255) & ~(size_t)255;
    return p;
  };
  int* cnt_p  = (int*)take((size_t)n * 4);
  int* cnt_n  = (int*)take((size_t)n * 4);
  int* tots   = (int*)take(8);
  int* off_p  = (int*)take((size_t)n * 4);
  int* off_n  = (int*)take((size_t)n * 4);
  int* cur_p  = (int*)take((size_t)n * 4);
  int* cur_n  = (int*)take((size_t)n * 4);
  int* list_p = (int*)take((size_t)e * 4);
  int* list_n = (int*)take((size_t)e * 4);
  float* Mp = (float*)take((size_t)n * 64 * 4);   // n*64*4 is 256B-multiple => Mn contiguous
  float* Mn = (float*)take((size_t)n * 64 * 4);
  float* z  = (float*)take((size_t)n * 128 * 4);
  float* An = (float*)take((size_t)n * 128 * 4);
  float* Ap = Mp;  // alias: Mp/Mn dead after lin1; Ap spans both (n*128 floats)

  hipMemsetAsync(cnt_p, 0, (size_t)n * 4, stream);
  hipMemsetAsync(cnt_n, 0, (size_t)n * 4, stream);
  hipMemsetAsync(tots, 0, 8, stream);

  int blkE = (2 * e + 255) / 256;
  count_kernel<<<blkE, 256, 0, stream>>>(pei, nei, cnt_p, cnt_n, e);
  alloc_kernel<<<(n + 255) / 256, 256, 0, stream>>>(cnt_p, cnt_n, off_p, off_n, cur_p, cur_n, tots, n);
  fill_kernel<<<blkE, 256, 0, stream>>>(pei, nei, cur_p, cur_n, list_p, list_n, e);

  // layer 1
  agg1_kernel<<<(2 * n * 64 + 255) / 256, 256, 0, stream>>>(
      x, off_p, cnt_p, list_p, off_n, cnt_n, list_n, Mp, Mn, n);
  dim3 g1(640, 2);
  lin1_kernel<<<g1, 1024, 0, stream>>>(x, Mp, Mn, Wp1, bp1, Wn1, bn1, z, n);

  // layer 2
  agg2_kernel<<<(4 * n * 64 + 255) / 256, 256, 0, stream>>>(
      z, off_p, cnt_p, list_p, off_n, cnt_n, list_n, Ap, An, n);
  lin2_kernel<<<g1, 1024, 0, stream>>>(z, Ap, An, Wp2, bp2, Wn2, bn2, out, n);
}

// Round 5
// 1529.763 us; speedup vs baseline: 3.9608x; 2.4278x over previous
//
#include <hip/hip_runtime.h>

// SignedGCN on MI355X. Pull-style aggregation via on-device CSR build.
// R5: aggs/CSR = R2 (proven). Linears = R2 mapping + 4 named accumulators
// + 2 rows/wave, blockDim 256, __launch_bounds__(256,4) (VGPR cap 128,
// est ~70 -> no spills; R3/R4 regressions were scratch spill traffic).

__global__ void count_kernel(const int* __restrict__ pei, const int* __restrict__ nei,
                             int* __restrict__ cnt_p, int* __restrict__ cnt_n, int e) {
  int i = blockIdx.x * blockDim.x + threadIdx.x;
  if (i < e) {
    atomicAdd(&cnt_p[pei[e + i]], 1);
  } else if (i < 2 * e) {
    atomicAdd(&cnt_n[nei[e + (i - e)]], 1);
  }
}

__global__ void alloc_kernel(const int* __restrict__ cnt_p, const int* __restrict__ cnt_n,
                             int* __restrict__ off_p, int* __restrict__ off_n,
                             int* __restrict__ cur_p, int* __restrict__ cur_n,
                             int* __restrict__ tots, int n) {
  int v = blockIdx.x * blockDim.x + threadIdx.x;
  int lane = threadIdx.x & 63;
  int vp = (v < n) ? cnt_p[v] : 0;
  int vn = (v < n) ? cnt_n[v] : 0;
  int sp = vp, sn = vn;
  #pragma unroll
  for (int d = 1; d < 64; d <<= 1) {
    int tp = __shfl_up(sp, d);
    int tn = __shfl_up(sn, d);
    if (lane >= d) { sp += tp; sn += tn; }
  }
  int basep = 0, basen = 0;
  if (lane == 63) {
    basep = atomicAdd(&tots[0], sp);
    basen = atomicAdd(&tots[1], sn);
  }
  basep = __shfl(basep, 63);
  basen = __shfl(basen, 63);
  if (v < n) {
    int op = basep + sp - vp;
    int on = basen + sn - vn;
    off_p[v] = op; cur_p[v] = op;
    off_n[v] = on; cur_n[v] = on;
  }
}

__global__ void fill_kernel(const int* __restrict__ pei, const int* __restrict__ nei,
                            int* __restrict__ cur_p, int* __restrict__ cur_n,
                            int* __restrict__ list_p, int* __restrict__ list_n, int e) {
  int i = blockIdx.x * blockDim.x + threadIdx.x;
  if (i < e) {
    int dst = pei[e + i];
    int p = atomicAdd(&cur_p[dst], 1);
    list_p[p] = pei[i];
  } else if (i < 2 * e) {
    int j = i - e;
    int dst = nei[e + j];
    int p = atomicAdd(&cur_n[dst], 1);
    list_n[p] = nei[j];
  }
}

// Layer-1 aggregation: wave per (node, graph); lane = channel (64 ch). [R2-proven]
__global__ void agg1_kernel(const float* __restrict__ x,
                            const int* __restrict__ off_p, const int* __restrict__ cnt_p, const int* __restrict__ list_p,
                            const int* __restrict__ off_n, const int* __restrict__ cnt_n, const int* __restrict__ list_n,
                            float* __restrict__ Mp, float* __restrict__ Mn, int n) {
  int wid = (blockIdx.x * blockDim.x + threadIdx.x) >> 6;
  int lane = threadIdx.x & 63;
  int v = wid >> 1;
  if (v >= n) return;
  int g = wid & 1;
  const int* off = g ? off_n : off_p;
  const int* cnt = g ? cnt_n : cnt_p;
  const int* lst = g ? list_n : list_p;
  float* M = g ? Mn : Mp;
  int d = cnt[v], o = off[v];
  float acc = 0.f;
  int i = 0;
  for (; i + 4 <= d; i += 4) {
    int s0 = lst[o + i], s1 = lst[o + i + 1], s2 = lst[o + i + 2], s3 = lst[o + i + 3];
    acc += x[(size_t)s0 * 64 + lane];
    acc += x[(size_t)s1 * 64 + lane];
    acc += x[(size_t)s2 * 64 + lane];
    acc += x[(size_t)s3 * 64 + lane];
  }
  for (; i < d; ++i) acc += x[(size_t)lst[o + i] * 64 + lane];
  M[(size_t)v * 64 + lane] = acc / (float)(d > 0 ? d : 1);
}

// Layer-2 aggregation over z (128 ch): wave per (node, graph, half64). [R2-proven]
__global__ void agg2_kernel(const float* __restrict__ z,
                            const int* __restrict__ off_p, const int* __restrict__ cnt_p, const int* __restrict__ list_p,
                            const int* __restrict__ off_n, const int* __restrict__ cnt_n, const int* __restrict__ list_n,
                            float* __restrict__ Ap, float* __restrict__ An, int n) {
  int wid = (blockIdx.x * blockDim.x + threadIdx.x) >> 6;
  int lane = threadIdx.x & 63;
  int v = wid >> 2;
  if (v >= n) return;
  int g = (wid >> 1) & 1;
  int h = wid & 1;
  const int* off = g ? off_n : off_p;
  const int* cnt = g ? cnt_n : cnt_p;
  const int* lst = g ? list_n : list_p;
  float* A = g ? An : Ap;
  int d = cnt[v], o = off[v];
  int c = h * 64 + lane;
  float acc = 0.f;
  int i = 0;
  for (; i + 4 <= d; i += 4) {
    int s0 = lst[o + i], s1 = lst[o + i + 1], s2 = lst[o + i + 2], s3 = lst[o + i + 3];
    acc += z[(size_t)s0 * 128 + c];
    acc += z[(size_t)s1 * 128 + c];
    acc += z[(size_t)s2 * 128 + c];
    acc += z[(size_t)s3 * 128 + c];
  }
  for (; i < d; ++i) acc += z[(size_t)lst[o + i] * 128 + c];
  A[(size_t)v * 128 + c] = acc / (float)(d > 0 ? d : 1);
}

// z[:, half*64 + lane] = relu([M, x] @ W.T + b). Wave = 2 rows, lane = out col.
// 4 independent accumulators/row; 256-thread blocks so VGPR cap is 128 (no spill).
__global__ __launch_bounds__(256, 4) void lin1_kernel(
    const float* __restrict__ x, const float* __restrict__ Mp, const float* __restrict__ Mn,
    const float* __restrict__ Wp1, const float* __restrict__ bp1,
    const float* __restrict__ Wn1, const float* __restrict__ bn1,
    float* __restrict__ z, int n) {
  __shared__ float Wt[128 * 64];  // Wt[k][j] = W[j][k], 32 KiB
  int half = blockIdx.y;
  const float* W  = half ? Wn1 : Wp1;
  const float* bb = half ? bn1 : bp1;
  const float* M  = half ? Mn : Mp;
  for (int f = threadIdx.x; f < 128 * 64; f += 256) {
    int k = f >> 6, j = f & 63;
    Wt[f] = W[j * 128 + k];
  }
  __syncthreads();
  int lane = threadIdx.x & 63;
  float bias = bb[lane];
  int gw = blockIdx.x * 4 + (threadIdx.x >> 6);
  int wstride = gridDim.x * 4;
  for (int v0 = gw * 2; v0 < n; v0 += wstride * 2) {
    int v1 = (v0 + 1 < n) ? v0 + 1 : v0;
    const float4* m0 = (const float4*)(M + (size_t)v0 * 64);
    const float4* m1 = (const float4*)(M + (size_t)v1 * 64);
    const float4* x0 = (const float4*)(x + (size_t)v0 * 64);
    const float4* x1 = (const float4*)(x + (size_t)v1 * 64);
    float a0 = bias, a1 = 0.f, a2 = 0.f, a3 = 0.f;
    float b0 = bias, b1 = 0.f, b2 = 0.f, b3 = 0.f;
    #pragma unroll 4
    for (int k4 = 0; k4 < 16; ++k4) {
      float4 u0 = m0[k4];
      float4 u1 = m1[k4];
      float w0 = Wt[(k4 * 4 + 0) * 64 + lane];
      float w1 = Wt[(k4 * 4 + 1) * 64 + lane];
      float w2 = Wt[(k4 * 4 + 2) * 64 + lane];
      float w3 = Wt[(k4 * 4 + 3) * 64 + lane];
      a0 = fmaf(u0.x, w0, a0); a1 = fmaf(u0.y, w1, a1);
      a2 = fmaf(u0.z, w2, a2); a3 = fmaf(u0.w, w3, a3);
      b0 = fmaf(u1.x, w0, b0); b1 = fmaf(u1.y, w1, b1);
      b2 = fmaf(u1.z, w2, b2); b3 = fmaf(u1.w, w3, b3);
    }
    #pragma unroll 4
    for (int k4 = 0; k4 < 16; ++k4) {
      float4 u0 = x0[k4];
      float4 u1 = x1[k4];
      float w0 = Wt[(64 + k4 * 4 + 0) * 64 + lane];
      float w1 = Wt[(64 + k4 * 4 + 1) * 64 + lane];
      float w2 = Wt[(64 + k4 * 4 + 2) * 64 + lane];
      float w3 = Wt[(64 + k4 * 4 + 3) * 64 + lane];
      a0 = fmaf(u0.x, w0, a0); a1 = fmaf(u0.y, w1, a1);
      a2 = fmaf(u0.z, w2, a2); a3 = fmaf(u0.w, w3, a3);
      b0 = fmaf(u1.x, w0, b0); b1 = fmaf(u1.y, w1, b1);
      b2 = fmaf(u1.z, w2, b2); b3 = fmaf(u1.w, w3, b3);
    }
    float r0 = (a0 + a1) + (a2 + a3);
    float r1 = (b0 + b1) + (b2 + b3);
    z[(size_t)v0 * 128 + half * 64 + lane] = fmaxf(r0, 0.f);
    if (v0 + 1 < n)
      z[(size_t)(v0 + 1) * 128 + half * 64 + lane] = fmaxf(r1, 0.f);
  }
}

// out[:, half*64+lane] = relu([A1, A2, Zr] @ W.T + b). Same structure, K=192.
__global__ __launch_bounds__(256, 4) void lin2_kernel(
    const float* __restrict__ z, const float* __restrict__ Ap, const float* __restrict__ An,
    const float* __restrict__ Wp2, const float* __restrict__ bp2,
    const float* __restrict__ Wn2, const float* __restrict__ bn2,
    float* __restrict__ out, int n) {
  __shared__ float Wt[192 * 64];  // 48 KiB
  int half = blockIdx.y;
  const float* W  = half ? Wn2 : Wp2;
  const float* bb = half ? bn2 : bp2;
  for (int f = threadIdx.x; f < 192 * 64; f += 256) {
    int k = f >> 6, j = f & 63;
    Wt[f] = W[j * 192 + k];
  }
  __syncthreads();
  int lane = threadIdx.x & 63;
  float bias = bb[lane];
  int gw = blockIdx.x * 4 + (threadIdx.x >> 6);
  int wstride = gridDim.x * 4;
  size_t a1off = half ? 64 : 0;   // Ap column offset
  size_t a2off = half ? 0 : 64;   // An column offset
  size_t zoff  = half ? 64 : 0;   // z  column offset
  for (int v0 = gw * 2; v0 < n; v0 += wstride * 2) {
    int v1 = (v0 + 1 < n) ? v0 + 1 : v0;
    const float4* p10 = (const float4*)(Ap + (size_t)v0 * 128 + a1off);
    const float4* p11 = (const float4*)(Ap + (size_t)v1 * 128 + a1off);
    const float4* p20 = (const float4*)(An + (size_t)v0 * 128 + a2off);
    const float4* p21 = (const float4*)(An + (size_t)v1 * 128 + a2off);
    const float4* p30 = (const float4*)(z  + (size_t)v0 * 128 + zoff);
    const float4* p31 = (const float4*)(z  + (size_t)v1 * 128 + zoff);
    float a0 = bias, a1 = 0.f, a2 = 0.f, a3 = 0.f;
    float b0 = bias, b1 = 0.f, b2 = 0.f, b3 = 0.f;
    #pragma unroll 4
    for (int k4 = 0; k4 < 16; ++k4) {
      float4 u0 = p10[k4];
      float4 u1 = p11[k4];
      float w0 = Wt[(k4 * 4 + 0) * 64 + lane];
      float w1 = Wt[(k4 * 4 + 1) * 64 + lane];
      float w2 = Wt[(k4 * 4 + 2) * 64 + lane];
      float w3 = Wt[(k4 * 4 + 3) * 64 + lane];
      a0 = fmaf(u0.x, w0, a0); a1 = fmaf(u0.y, w1, a1);
      a2 = fmaf(u0.z, w2, a2); a3 = fmaf(u0.w, w3, a3);
      b0 = fmaf(u1.x, w0, b0); b1 = fmaf(u1.y, w1, b1);
      b2 = fmaf(u1.z, w2, b2); b3 = fmaf(u1.w, w3, b3);
    }
    #pragma unroll 4
    for (int k4 = 0; k4 < 16; ++k4) {
      float4 u0 = p20[k4];
      float4 u1 = p21[k4];
      float w0 = Wt[(64 + k4 * 4 + 0) * 64 + lane];
      float w1 = Wt[(64 + k4 * 4 + 1) * 64 + lane];
      float w2 = Wt[(64 + k4 * 4 + 2) * 64 + lane];
      float w3 = Wt[(64 + k4 * 4 + 3) * 64 + lane];
      a0 = fmaf(u0.x, w0, a0); a1 = fmaf(u0.y, w1, a1);
      a2 = fmaf(u0.z, w2, a2); a3 = fmaf(u0.w, w3, a3);
      b0 = fmaf(u1.x, w0, b0); b1 = fmaf(u1.y, w1, b1);
      b2 = fmaf(u1.z, w2, b2); b3 = fmaf(u1.w, w3, b3);
    }
    #pragma unroll 4
    for (int k4 = 0; k4 < 16; ++k4) {
      float4 u0 = p30[k4];
      float4 u1 = p31[k4];
      float w0 = Wt[(128 + k4 * 4 + 0) * 64 + lane];
      float w1 = Wt[(128 + k4 * 4 + 1) * 64 + lane];
      float w2 = Wt[(128 + k4 * 4 + 2) * 64 + lane];
      float w3 = Wt[(128 + k4 * 4 + 3) * 64 + lane];
      a0 = fmaf(u0.x, w0, a0); a1 = fmaf(u0.y, w1, a1);
      a2 = fmaf(u0.z, w2, a2); a3 = fmaf(u0.w, w3, a3);
      b0 = fmaf(u1.x, w0, b0); b1 = fmaf(u1.y, w1, b1);
      b2 = fmaf(u1.z, w2, b2); b3 = fmaf(u1.w, w3, b3);
    }
    float r0 = (a0 + a1) + (a2 + a3);
    float r1 = (b0 + b1) + (b2 + b3);
    out[(size_t)v0 * 128 + half * 64 + lane] = fmaxf(r0, 0.f);
    if (v0 + 1 < n)
      out[(size_t)(v0 + 1) * 128 + half * 64 + lane] = fmaxf(r1, 0.f);
  }
}

extern "C" void kernel_launch(void* const* d_in, const int* in_sizes, int n_in,
                              void* d_out, int out_size, void* d_ws, size_t ws_size,
                              hipStream_t stream) {
  const float* x   = (const float*)d_in[0];
  const int*   pei = (const int*)d_in[1];
  const int*   nei = (const int*)d_in[2];
  const float* Wp1 = (const float*)d_in[3];
  const float* bp1 = (const float*)d_in[4];
  const float* Wn1 = (const float*)d_in[5];
  const float* bn1 = (const float*)d_in[6];
  const float* Wp2 = (const float*)d_in[7];
  const float* bp2 = (const float*)d_in[8];
  const float* Wn2 = (const float*)d_in[9];
  const float* bn2 = (const float*)d_in[10];
  float* out = (float*)d_out;

  const int n = in_sizes[0] / 64;   // 100000
  const int e = in_sizes[1] / 2;    // 1600000

  char* w = (char*)d_ws;
  size_t off = 0;
  auto take = [&](size_t bytes) -> void* {
    void* p = (void*)(w + off);
    off += (bytes + 255) & ~(size_t)255;
    return p;
  };
  int* cnt_p  = (int*)take((size_t)n * 4);
  int* cnt_n  = (int*)take((size_t)n * 4);
  int* tots   = (int*)take(8);
  int* off_p  = (int*)take((size_t)n * 4);
  int* off_n  = (int*)take((size_t)n * 4);
  int* cur_p  = (int*)take((size_t)n * 4);
  int* cur_n  = (int*)take((size_t)n * 4);
  int* list_p = (int*)take((size_t)e * 4);
  int* list_n = (int*)take((size_t)e * 4);
  float* Mp = (float*)take((size_t)n * 64 * 4);   // n*64*4 is 256B-multiple => Mn contiguous
  float* Mn = (float*)take((size_t)n * 64 * 4);
  float* z  = (float*)take((size_t)n * 128 * 4);
  float* An = (float*)take((size_t)n * 128 * 4);
  float* Ap = Mp;  // alias: Mp/Mn dead after lin1; Ap spans both (n*128 floats)

  hipMemsetAsync(cnt_p, 0, (size_t)n * 4, stream);
  hipMemsetAsync(cnt_n, 0, (size_t)n * 4, stream);
  hipMemsetAsync(tots, 0, 8, stream);

  int blkE = (2 * e + 255) / 256;
  count_kernel<<<blkE, 256, 0, stream>>>(pei, nei, cnt_p, cnt_n, e);
  alloc_kernel<<<(n + 255) / 256, 256, 0, stream>>>(cnt_p, cnt_n, off_p, off_n, cur_p, cur_n, tots, n);
  fill_kernel<<<blkE, 256, 0, stream>>>(pei, nei, cur_p, cur_n, list_p, list_n, e);

  // layer 1
  agg1_kernel<<<(2 * n * 64 + 255) / 256, 256, 0, stream>>>(
      x, off_p, cnt_p, list_p, off_n, cnt_n, list_n, Mp, Mn, n);
  dim3 g1(2048, 2);
  lin1_kernel<<<g1, 256, 0, stream>>>(x, Mp, Mn, Wp1, bp1, Wn1, bn1, z, n);

  // layer 2
  agg2_kernel<<<(4 * n * 64 + 255) / 256, 256, 0, stream>>>(
      z, off_p, cnt_p, list_p, off_n, cnt_n, list_n, Ap, An, n);
  lin2_kernel<<<g1, 256, 0, stream>>>(z, Ap, An, Wp2, bp2, Wn2, bn2, out, n);
}

// Round 6
// 1268.465 us; speedup vs baseline: 4.7767x; 1.2060x over previous
//
#include <hip/hip_runtime.h>

// SignedGCN on MI355X. Pull-style aggregation via on-device CSR build.
// R6: linears use [j][k] LDS weights + XOR-swizzled ds_read_b128 (conflict-free,
// coalesced fill), 4 rows/wave with 8 named accumulators, 512-thr blocks.
// z kept ONLY as bf16 (zh): halves agg2 gather traffic; lin2 Zr reads bf16.

__device__ __forceinline__ float bflo(unsigned u) { return __uint_as_float(u << 16); }
__device__ __forceinline__ float bfhi(unsigned u) { return __uint_as_float(u & 0xFFFF0000u); }
__device__ __forceinline__ unsigned short f2bf(float f) {
  unsigned u = __float_as_uint(f);
  return (unsigned short)((u + 0x7FFFu + ((u >> 16) & 1u)) >> 16);
}

__global__ void count_kernel(const int* __restrict__ pei, const int* __restrict__ nei,
                             int* __restrict__ cnt_p, int* __restrict__ cnt_n, int e) {
  int i = blockIdx.x * blockDim.x + threadIdx.x;
  if (i < e) {
    atomicAdd(&cnt_p[pei[e + i]], 1);
  } else if (i < 2 * e) {
    atomicAdd(&cnt_n[nei[e + (i - e)]], 1);
  }
}

__global__ void alloc_kernel(const int* __restrict__ cnt_p, const int* __restrict__ cnt_n,
                             int* __restrict__ off_p, int* __restrict__ off_n,
                             int* __restrict__ cur_p, int* __restrict__ cur_n,
                             int* __restrict__ tots, int n) {
  int v = blockIdx.x * blockDim.x + threadIdx.x;
  int lane = threadIdx.x & 63;
  int vp = (v < n) ? cnt_p[v] : 0;
  int vn = (v < n) ? cnt_n[v] : 0;
  int sp = vp, sn = vn;
  #pragma unroll
  for (int d = 1; d < 64; d <<= 1) {
    int tp = __shfl_up(sp, d);
    int tn = __shfl_up(sn, d);
    if (lane >= d) { sp += tp; sn += tn; }
  }
  int basep = 0, basen = 0;
  if (lane == 63) {
    basep = atomicAdd(&tots[0], sp);
    basen = atomicAdd(&tots[1], sn);
  }
  basep = __shfl(basep, 63);
  basen = __shfl(basen, 63);
  if (v < n) {
    int op = basep + sp - vp;
    int on = basen + sn - vn;
    off_p[v] = op; cur_p[v] = op;
    off_n[v] = on; cur_n[v] = on;
  }
}

__global__ void fill_kernel(const int* __restrict__ pei, const int* __restrict__ nei,
                            int* __restrict__ cur_p, int* __restrict__ cur_n,
                            int* __restrict__ list_p, int* __restrict__ list_n, int e) {
  int i = blockIdx.x * blockDim.x + threadIdx.x;
  if (i < e) {
    int dst = pei[e + i];
    int p = atomicAdd(&cur_p[dst], 1);
    list_p[p] = pei[i];
  } else if (i < 2 * e) {
    int j = i - e;
    int dst = nei[e + j];
    int p = atomicAdd(&cur_n[dst], 1);
    list_n[p] = nei[j];
  }
}

// Layer-1 aggregation: wave per (node, graph); lane = channel (64 ch). [R2-proven]
__global__ void agg1_kernel(const float* __restrict__ x,
                            const int* __restrict__ off_p, const int* __restrict__ cnt_p, const int* __restrict__ list_p,
                            const int* __restrict__ off_n, const int* __restrict__ cnt_n, const int* __restrict__ list_n,
                            float* __restrict__ Mp, float* __restrict__ Mn, int n) {
  int wid = (blockIdx.x * blockDim.x + threadIdx.x) >> 6;
  int lane = threadIdx.x & 63;
  int v = wid >> 1;
  if (v >= n) return;
  int g = wid & 1;
  const int* off = g ? off_n : off_p;
  const int* cnt = g ? cnt_n : cnt_p;
  const int* lst = g ? list_n : list_p;
  float* M = g ? Mn : Mp;
  int d = cnt[v], o = off[v];
  float acc = 0.f;
  int i = 0;
  for (; i + 4 <= d; i += 4) {
    int s0 = lst[o + i], s1 = lst[o + i + 1], s2 = lst[o + i + 2], s3 = lst[o + i + 3];
    acc += x[(size_t)s0 * 64 + lane];
    acc += x[(size_t)s1 * 64 + lane];
    acc += x[(size_t)s2 * 64 + lane];
    acc += x[(size_t)s3 * 64 + lane];
  }
  for (; i < d; ++i) acc += x[(size_t)lst[o + i] * 64 + lane];
  M[(size_t)v * 64 + lane] = acc / (float)(d > 0 ? d : 1);
}

// Layer-2 aggregation over bf16 z (zh): wave per (node, graph); lane covers 2 ch
// via one 4-B load (256 B coalesced per row), f32 accumulate, f32 output.
__global__ void agg2_kernel(const unsigned short* __restrict__ zh,
                            const int* __restrict__ off_p, const int* __restrict__ cnt_p, const int* __restrict__ list_p,
                            const int* __restrict__ off_n, const int* __restrict__ cnt_n, const int* __restrict__ list_n,
                            float* __restrict__ Ap, float* __restrict__ An, int n) {
  int wid = (blockIdx.x * blockDim.x + threadIdx.x) >> 6;
  int lane = threadIdx.x & 63;
  int v = wid >> 1;
  if (v >= n) return;
  int g = wid & 1;
  const int* off = g ? off_n : off_p;
  const int* cnt = g ? cnt_n : cnt_p;
  const int* lst = g ? list_n : list_p;
  float* A = g ? An : Ap;
  int d = cnt[v], o = off[v];
  float acc0 = 0.f, acc1 = 0.f;
  int i = 0;
  for (; i + 4 <= d; i += 4) {
    int s0 = lst[o + i], s1 = lst[o + i + 1], s2 = lst[o + i + 2], s3 = lst[o + i + 3];
    unsigned u0 = *(const unsigned*)(zh + (size_t)s0 * 128 + lane * 2);
    unsigned u1 = *(const unsigned*)(zh + (size_t)s1 * 128 + lane * 2);
    unsigned u2 = *(const unsigned*)(zh + (size_t)s2 * 128 + lane * 2);
    unsigned u3 = *(const unsigned*)(zh + (size_t)s3 * 128 + lane * 2);
    acc0 += bflo(u0) + bflo(u1) + bflo(u2) + bflo(u3);
    acc1 += bfhi(u0) + bfhi(u1) + bfhi(u2) + bfhi(u3);
  }
  for (; i < d; ++i) {
    unsigned u = *(const unsigned*)(zh + (size_t)lst[o + i] * 128 + lane * 2);
    acc0 += bflo(u);
    acc1 += bfhi(u);
  }
  float inv = 1.f / (float)(d > 0 ? d : 1);
  *(float2*)(A + (size_t)v * 128 + lane * 2) = make_float2(acc0 * inv, acc1 * inv);
}

// zh[:, half*64 + lane] = bf16(relu([M, x] @ W.T + b)).
// Wave = 4 rows, lane = out col. Weights in LDS as [j][k4-swizzled] float4;
// lane reads its own column with conflict-free ds_read_b128.
__global__ __launch_bounds__(512, 4) void lin1_kernel(
    const float* __restrict__ x, const float* __restrict__ Mp, const float* __restrict__ Mn,
    const float* __restrict__ Wp1, const float* __restrict__ bp1,
    const float* __restrict__ Wn1, const float* __restrict__ bn1,
    unsigned short* __restrict__ zh, int n) {
  __shared__ float Wt[64 * 128];  // 32 KiB, [j][k] with k4 XOR-swizzle
  int half = blockIdx.y;
  const float* W  = half ? Wn1 : Wp1;
  const float* bb = half ? bn1 : bp1;
  const float* M  = half ? Mn : Mp;
  for (int f = threadIdx.x; f < 64 * 128; f += 512) {
    int j = f >> 7, k = f & 127;
    int k4 = k >> 2, kr = k & 3;
    Wt[(j * 32 + (k4 ^ (j & 7))) * 4 + kr] = W[f];  // coalesced global read
  }
  __syncthreads();
  int lane = threadIdx.x & 63;
  float bias = bb[lane];
  int wrow = lane * 32;      // lane's weight row, float4 units
  int wsw = lane & 7;        // XOR key
  int gw = blockIdx.x * 8 + (threadIdx.x >> 6);
  int wstride = gridDim.x * 8;
  for (int v0 = gw * 4; v0 < n; v0 += wstride * 4) {
    int vB = (v0 + 1 < n) ? v0 + 1 : v0;
    int vC = (v0 + 2 < n) ? v0 + 2 : v0;
    int vD = (v0 + 3 < n) ? v0 + 3 : v0;
    const float4* mA = (const float4*)(M + (size_t)v0 * 64);
    const float4* mB = (const float4*)(M + (size_t)vB * 64);
    const float4* mC = (const float4*)(M + (size_t)vC * 64);
    const float4* mD = (const float4*)(M + (size_t)vD * 64);
    const float4* xA = (const float4*)(x + (size_t)v0 * 64);
    const float4* xB = (const float4*)(x + (size_t)vB * 64);
    const float4* xC = (const float4*)(x + (size_t)vC * 64);
    const float4* xD = (const float4*)(x + (size_t)vD * 64);
    float aA0 = bias, aA1 = 0.f, aB0 = bias, aB1 = 0.f;
    float aC0 = bias, aC1 = 0.f, aD0 = bias, aD1 = 0.f;
    #pragma unroll 2
    for (int k4 = 0; k4 < 16; ++k4) {
      float4 w4 = *(const float4*)&Wt[(wrow + (k4 ^ wsw)) * 4];
      float4 uA = mA[k4]; float4 uB = mB[k4]; float4 uC = mC[k4]; float4 uD = mD[k4];
      aA0 = fmaf(uA.x, w4.x, aA0); aA1 = fmaf(uA.y, w4.y, aA1);
      aA0 = fmaf(uA.z, w4.z, aA0); aA1 = fmaf(uA.w, w4.w, aA1);
      aB0 = fmaf(uB.x, w4.x, aB0); aB1 = fmaf(uB.y, w4.y, aB1);
      aB0 = fmaf(uB.z, w4.z, aB0); aB1 = fmaf(uB.w, w4.w, aB1);
      aC0 = fmaf(uC.x, w4.x, aC0); aC1 = fmaf(uC.y, w4.y, aC1);
      aC0 = fmaf(uC.z, w4.z, aC0); aC1 = fmaf(uC.w, w4.w, aC1);
      aD0 = fmaf(uD.x, w4.x, aD0); aD1 = fmaf(uD.y, w4.y, aD1);
      aD0 = fmaf(uD.z, w4.z, aD0); aD1 = fmaf(uD.w, w4.w, aD1);
    }
    #pragma unroll 2
    for (int k4 = 16; k4 < 32; ++k4) {
      float4 w4 = *(const float4*)&Wt[(wrow + (k4 ^ wsw)) * 4];
      int kk = k4 - 16;
      float4 uA = xA[kk]; float4 uB = xB[kk]; float4 uC = xC[kk]; float4 uD = xD[kk];
      aA0 = fmaf(uA.x, w4.x, aA0); aA1 = fmaf(uA.y, w4.y, aA1);
      aA0 = fmaf(uA.z, w4.z, aA0); aA1 = fmaf(uA.w, w4.w, aA1);
      aB0 = fmaf(uB.x, w4.x, aB0); aB1 = fmaf(uB.y, w4.y, aB1);
      aB0 = fmaf(uB.z, w4.z, aB0); aB1 = fmaf(uB.w, w4.w, aB1);
      aC0 = fmaf(uC.x, w4.x, aC0); aC1 = fmaf(uC.y, w4.y, aC1);
      aC0 = fmaf(uC.z, w4.z, aC0); aC1 = fmaf(uC.w, w4.w, aC1);
      aD0 = fmaf(uD.x, w4.x, aD0); aD1 = fmaf(uD.y, w4.y, aD1);
      aD0 = fmaf(uD.z, w4.z, aD0); aD1 = fmaf(uD.w, w4.w, aD1);
    }
    size_t col = (size_t)half * 64 + lane;
    zh[(size_t)v0 * 128 + col] = f2bf(fmaxf(aA0 + aA1, 0.f));
    if (v0 + 1 < n) zh[(size_t)(v0 + 1) * 128 + col] = f2bf(fmaxf(aB0 + aB1, 0.f));
    if (v0 + 2 < n) zh[(size_t)(v0 + 2) * 128 + col] = f2bf(fmaxf(aC0 + aC1, 0.f));
    if (v0 + 3 < n) zh[(size_t)(v0 + 3) * 128 + col] = f2bf(fmaxf(aD0 + aD1, 0.f));
  }
}

// out[:, half*64+lane] = relu([A1, A2, Zr] @ W.T + b); A f32, Zr bf16. K=192.
__global__ __launch_bounds__(512, 4) void lin2_kernel(
    const unsigned short* __restrict__ zh, const float* __restrict__ Ap, const float* __restrict__ An,
    const float* __restrict__ Wp2, const float* __restrict__ bp2,
    const float* __restrict__ Wn2, const float* __restrict__ bn2,
    float* __restrict__ out, int n) {
  __shared__ float Wt[64 * 192];  // 48 KiB
  int half = blockIdx.y;
  const float* W  = half ? Wn2 : Wp2;
  const float* bb = half ? bn2 : bp2;
  for (int f = threadIdx.x; f < 64 * 192; f += 512) {
    int j = f / 192, k = f - j * 192;
    int k4 = k >> 2, kr = k & 3;
    Wt[(j * 48 + (k4 ^ (j & 7))) * 4 + kr] = W[f];  // coalesced global read
  }
  __syncthreads();
  int lane = threadIdx.x & 63;
  float bias = bb[lane];
  int wrow = lane * 48;
  int wsw = lane & 7;
  int gw = blockIdx.x * 8 + (threadIdx.x >> 6);
  int wstride = gridDim.x * 8;
  size_t a1off = half ? 64 : 0;   // Ap column offset
  size_t a2off = half ? 0 : 64;   // An column offset
  size_t zoff  = half ? 64 : 0;   // zh column offset
  for (int v0 = gw * 4; v0 < n; v0 += wstride * 4) {
    int vB = (v0 + 1 < n) ? v0 + 1 : v0;
    int vC = (v0 + 2 < n) ? v0 + 2 : v0;
    int vD = (v0 + 3 < n) ? v0 + 3 : v0;
    const float4* p1A = (const float4*)(Ap + (size_t)v0 * 128 + a1off);
    const float4* p1B = (const float4*)(Ap + (size_t)vB * 128 + a1off);
    const float4* p1C = (const float4*)(Ap + (size_t)vC * 128 + a1off);
    const float4* p1D = (const float4*)(Ap + (size_t)vD * 128 + a1off);
    float aA0 = bias, aA1 = 0.f, aB0 = bias, aB1 = 0.f;
    float aC0 = bias, aC1 = 0.f, aD0 = bias, aD1 = 0.f;
    #pragma unroll 2
    for (int k4 = 0; k4 < 16; ++k4) {
      float4 w4 = *(const float4*)&Wt[(wrow + (k4 ^ wsw)) * 4];
      float4 uA = p1A[k4]; float4 uB = p1B[k4]; float4 uC = p1C[k4]; float4 uD = p1D[k4];
      aA0 = fmaf(uA.x, w4.x, aA0); aA1 = fmaf(uA.y, w4.y, aA1);
      aA0 = fmaf(uA.z, w4.z, aA0); aA1 = fmaf(uA.w, w4.w, aA1);
      aB0 = fmaf(uB.x, w4.x, aB0); aB1 = fmaf(uB.y, w4.y, aB1);
      aB0 = fmaf(uB.z, w4.z, aB0); aB1 = fmaf(uB.w, w4.w, aB1);
      aC0 = fmaf(uC.x, w4.x, aC0); aC1 = fmaf(uC.y, w4.y, aC1);
      aC0 = fmaf(uC.z, w4.z, aC0); aC1 = fmaf(uC.w, w4.w, aC1);
      aD0 = fmaf(uD.x, w4.x, aD0); aD1 = fmaf(uD.y, w4.y, aD1);
      aD0 = fmaf(uD.z, w4.z, aD0); aD1 = fmaf(uD.w, w4.w, aD1);
    }
    const float4* p2A = (const float4*)(An + (size_t)v0 * 128 + a2off);
    const float4* p2B = (const float4*)(An + (size_t)vB * 128 + a2off);
    const float4* p2C = (const float4*)(An + (size_t)vC * 128 + a2off);
    const float4* p2D = (const float4*)(An + (size_t)vD * 128 + a2off);
    #pragma unroll 2
    for (int k4 = 16; k4 < 32; ++k4) {
      float4 w4 = *(const float4*)&Wt[(wrow + (k4 ^ wsw)) * 4];
      int kk = k4 - 16;
      float4 uA = p2A[kk]; float4 uB = p2B[kk]; float4 uC = p2C[kk]; float4 uD = p2D[kk];
      aA0 = fmaf(uA.x, w4.x, aA0); aA1 = fmaf(uA.y, w4.y, aA1);
      aA0 = fmaf(uA.z, w4.z, aA0); aA1 = fmaf(uA.w, w4.w, aA1);
      aB0 = fmaf(uB.x, w4.x, aB0); aB1 = fmaf(uB.y, w4.y, aB1);
      aB0 = fmaf(uB.z, w4.z, aB0); aB1 = fmaf(uB.w, w4.w, aB1);
      aC0 = fmaf(uC.x, w4.x, aC0); aC1 = fmaf(uC.y, w4.y, aC1);
      aC0 = fmaf(uC.z, w4.z, aC0); aC1 = fmaf(uC.w, w4.w, aC1);
      aD0 = fmaf(uD.x, w4.x, aD0); aD1 = fmaf(uD.y, w4.y, aD1);
      aD0 = fmaf(uD.z, w4.z, aD0); aD1 = fmaf(uD.w, w4.w, aD1);
    }
    const unsigned short* zA = zh + (size_t)v0 * 128 + zoff;
    const unsigned short* zB = zh + (size_t)vB * 128 + zoff;
    const unsigned short* zC = zh + (size_t)vC * 128 + zoff;
    const unsigned short* zD = zh + (size_t)vD * 128 + zoff;
    #pragma unroll 2
    for (int k4 = 32; k4 < 48; ++k4) {
      float4 w4 = *(const float4*)&Wt[(wrow + (k4 ^ wsw)) * 4];
      int kk = k4 - 32;
      uint2 qA = *(const uint2*)(zA + (kk << 2));
      uint2 qB = *(const uint2*)(zB + (kk << 2));
      uint2 qC = *(const uint2*)(zC + (kk << 2));
      uint2 qD = *(const uint2*)(zD + (kk << 2));
      aA0 = fmaf(bflo(qA.x), w4.x, aA0); aA1 = fmaf(bfhi(qA.x), w4.y, aA1);
      aA0 = fmaf(bflo(qA.y), w4.z, aA0); aA1 = fmaf(bfhi(qA.y), w4.w, aA1);
      aB0 = fmaf(bflo(qB.x), w4.x, aB0); aB1 = fmaf(bfhi(qB.x), w4.y, aB1);
      aB0 = fmaf(bflo(qB.y), w4.z, aB0); aB1 = fmaf(bfhi(qB.y), w4.w, aB1);
      aC0 = fmaf(bflo(qC.x), w4.x, aC0); aC1 = fmaf(bfhi(qC.x), w4.y, aC1);
      aC0 = fmaf(bflo(qC.y), w4.z, aC0); aC1 = fmaf(bfhi(qC.y), w4.w, aC1);
      aD0 = fmaf(bflo(qD.x), w4.x, aD0); aD1 = fmaf(bfhi(qD.x), w4.y, aD1);
      aD0 = fmaf(bflo(qD.y), w4.z, aD0); aD1 = fmaf(bfhi(qD.y), w4.w, aD1);
    }
    size_t col = (size_t)half * 64 + lane;
    out[(size_t)v0 * 128 + col] = fmaxf(aA0 + aA1, 0.f);
    if (v0 + 1 < n) out[(size_t)(v0 + 1) * 128 + col] = fmaxf(aB0 + aB1, 0.f);
    if (v0 + 2 < n) out[(size_t)(v0 + 2) * 128 + col] = fmaxf(aC0 + aC1, 0.f);
    if (v0 + 3 < n) out[(size_t)(v0 + 3) * 128 + col] = fmaxf(aD0 + aD1, 0.f);
  }
}

extern "C" void kernel_launch(void* const* d_in, const int* in_sizes, int n_in,
                              void* d_out, int out_size, void* d_ws, size_t ws_size,
                              hipStream_t stream) {
  const float* x   = (const float*)d_in[0];
  const int*   pei = (const int*)d_in[1];
  const int*   nei = (const int*)d_in[2];
  const float* Wp1 = (const float*)d_in[3];
  const float* bp1 = (const float*)d_in[4];
  const float* Wn1 = (const float*)d_in[5];
  const float* bn1 = (const float*)d_in[6];
  const float* Wp2 = (const float*)d_in[7];
  const float* bp2 = (const float*)d_in[8];
  const float* Wn2 = (const float*)d_in[9];
  const float* bn2 = (const float*)d_in[10];
  float* out = (float*)d_out;

  const int n = in_sizes[0] / 64;   // 100000
  const int e = in_sizes[1] / 2;    // 1600000

  char* w = (char*)d_ws;
  size_t off = 0;
  auto take = [&](size_t bytes) -> void* {
    void* p = (void*)(w + off);
    off += (bytes + 255) & ~(size_t)255;
    return p;
  };
  int* cnt_p  = (int*)take((size_t)n * 4);
  int* cnt_n  = (int*)take((size_t)n * 4);
  int* tots   = (int*)take(8);
  int* off_p  = (int*)take((size_t)n * 4);
  int* off_n  = (int*)take((size_t)n * 4);
  int* cur_p  = (int*)take((size_t)n * 4);
  int* cur_n  = (int*)take((size_t)n * 4);
  int* list_p = (int*)take((size_t)e * 4);
  int* list_n = (int*)take((size_t)e * 4);
  float* Mp = (float*)take((size_t)n * 64 * 4);   // 256B-multiple => Mn contiguous
  float* Mn = (float*)take((size_t)n * 64 * 4);
  unsigned short* zh = (unsigned short*)take((size_t)n * 128 * 2);
  float* An = (float*)take((size_t)n * 128 * 4);
  float* Ap = Mp;  // alias: Mp/Mn dead after lin1; Ap spans both (n*128 floats)

  hipMemsetAsync(cnt_p, 0, (size_t)n * 4, stream);
  hipMemsetAsync(cnt_n, 0, (size_t)n * 4, stream);
  hipMemsetAsync(tots, 0, 8, stream);

  int blkE = (2 * e + 255) / 256;
  count_kernel<<<blkE, 256, 0, stream>>>(pei, nei, cnt_p, cnt_n, e);
  alloc_kernel<<<(n + 255) / 256, 256, 0, stream>>>(cnt_p, cnt_n, off_p, off_n, cur_p, cur_n, tots, n);
  fill_kernel<<<blkE, 256, 0, stream>>>(pei, nei, cur_p, cur_n, list_p, list_n, e);

  // layer 1
  agg1_kernel<<<(2 * n * 64 + 255) / 256, 256, 0, stream>>>(
      x, off_p, cnt_p, list_p, off_n, cnt_n, list_n, Mp, Mn, n);
  dim3 gl(768, 2);
  lin1_kernel<<<gl, 512, 0, stream>>>(x, Mp, Mn, Wp1, bp1, Wn1, bn1, zh, n);

  // layer 2
  agg2_kernel<<<(2 * n * 64 + 255) / 256, 256, 0, stream>>>(
      zh, off_p, cnt_p, list_p, off_n, cnt_n, list_n, Ap, An, n);
  lin2_kernel<<<gl, 512, 0, stream>>>(zh, Ap, An, Wp2, bp2, Wn2, bn2, out, n);
}

// Round 7
// 1065.418 us; speedup vs baseline: 5.6871x; 1.1906x over previous
//
#include <hip/hip_runtime.h>

// SignedGCN on MI355X. Pull-style aggregation via on-device CSR build.
// R7: count stores each edge's slot (coalesced) -> fill has NO atomics.
// fill is dst-partitioned into 4 passes (active write region 3.2MB < 4MB
// per-XCD L2) to kill the 16x dirty-line write amplification seen in R6.
// aggs: unroll 8 (more outstanding gathers). Linears unchanged from R6.

__device__ __forceinline__ float bflo(unsigned u) { return __uint_as_float(u << 16); }
__device__ __forceinline__ float bfhi(unsigned u) { return __uint_as_float(u & 0xFFFF0000u); }
__device__ __forceinline__ unsigned short f2bf(float f) {
  unsigned u = __float_as_uint(f);
  return (unsigned short)((u + 0x7FFFu + ((u >> 16) & 1u)) >> 16);
}

// Count degrees AND record each edge's slot within its destination's list.
__global__ void count_kernel(const int* __restrict__ pei, const int* __restrict__ nei,
                             int* __restrict__ cnt_p, int* __restrict__ cnt_n,
                             int* __restrict__ slot_p, int* __restrict__ slot_n, int e) {
  int i = blockIdx.x * blockDim.x + threadIdx.x;
  if (i < e) {
    slot_p[i] = atomicAdd(&cnt_p[pei[e + i]], 1);
  } else if (i < 2 * e) {
    int j = i - e;
    slot_n[j] = atomicAdd(&cnt_n[nei[e + j]], 1);
  }
}

// Exclusive offsets via wave-level scan + one atomic bump per wave per graph.
__global__ void alloc_kernel(const int* __restrict__ cnt_p, const int* __restrict__ cnt_n,
                             int* __restrict__ off_p, int* __restrict__ off_n,
                             int* __restrict__ tots, int n) {
  int v = blockIdx.x * blockDim.x + threadIdx.x;
  int lane = threadIdx.x & 63;
  int vp = (v < n) ? cnt_p[v] : 0;
  int vn = (v < n) ? cnt_n[v] : 0;
  int sp = vp, sn = vn;
  #pragma unroll
  for (int d = 1; d < 64; d <<= 1) {
    int tp = __shfl_up(sp, d);
    int tn = __shfl_up(sn, d);
    if (lane >= d) { sp += tp; sn += tn; }
  }
  int basep = 0, basen = 0;
  if (lane == 63) {
    basep = atomicAdd(&tots[0], sp);
    basen = atomicAdd(&tots[1], sn);
  }
  basep = __shfl(basep, 63);
  basen = __shfl(basen, 63);
  if (v < n) {
    off_p[v] = basep + sp - vp;
    off_n[v] = basen + sn - vn;
  }
}

// Atomic-free scatter fill, 4 dst-partitioned passes for L2 write locality.
__global__ void fill_kernel(const int* __restrict__ pei, const int* __restrict__ nei,
                            const int* __restrict__ off_p, const int* __restrict__ off_n,
                            const int* __restrict__ slot_p, const int* __restrict__ slot_n,
                            int* __restrict__ list_p, int* __restrict__ list_n,
                            int e, int n) {
  int stride = gridDim.x * blockDim.x;
  int nq = (n + 3) >> 2;
  for (int pass = 0; pass < 4; ++pass) {
    int lo = pass * nq;
    int hi = lo + nq; if (hi > n) hi = n;
    for (int i = blockIdx.x * blockDim.x + threadIdx.x; i < 2 * e; i += stride) {
      if (i < e) {
        int dst = pei[e + i];
        if (dst >= lo && dst < hi) list_p[off_p[dst] + slot_p[i]] = pei[i];
      } else {
        int j = i - e;
        int dst = nei[e + j];
        if (dst >= lo && dst < hi) list_n[off_n[dst] + slot_n[j]] = nei[j];
      }
    }
  }
}

// Layer-1 aggregation: wave per (node, graph); lane = channel (64 ch). Unroll 8.
__global__ void agg1_kernel(const float* __restrict__ x,
                            const int* __restrict__ off_p, const int* __restrict__ cnt_p, const int* __restrict__ list_p,
                            const int* __restrict__ off_n, const int* __restrict__ cnt_n, const int* __restrict__ list_n,
                            float* __restrict__ Mp, float* __restrict__ Mn, int n) {
  int wid = (blockIdx.x * blockDim.x + threadIdx.x) >> 6;
  int lane = threadIdx.x & 63;
  int v = wid >> 1;
  if (v >= n) return;
  int g = wid & 1;
  const int* off = g ? off_n : off_p;
  const int* cnt = g ? cnt_n : cnt_p;
  const int* lst = g ? list_n : list_p;
  float* M = g ? Mn : Mp;
  int d = cnt[v], o = off[v];
  float acc = 0.f;
  int i = 0;
  for (; i + 8 <= d; i += 8) {
    int s0 = lst[o + i],     s1 = lst[o + i + 1], s2 = lst[o + i + 2], s3 = lst[o + i + 3];
    int s4 = lst[o + i + 4], s5 = lst[o + i + 5], s6 = lst[o + i + 6], s7 = lst[o + i + 7];
    float r0 = x[(size_t)s0 * 64 + lane];
    float r1 = x[(size_t)s1 * 64 + lane];
    float r2 = x[(size_t)s2 * 64 + lane];
    float r3 = x[(size_t)s3 * 64 + lane];
    float r4 = x[(size_t)s4 * 64 + lane];
    float r5 = x[(size_t)s5 * 64 + lane];
    float r6 = x[(size_t)s6 * 64 + lane];
    float r7 = x[(size_t)s7 * 64 + lane];
    acc += ((r0 + r1) + (r2 + r3)) + ((r4 + r5) + (r6 + r7));
  }
  for (; i < d; ++i) acc += x[(size_t)lst[o + i] * 64 + lane];
  M[(size_t)v * 64 + lane] = acc / (float)(d > 0 ? d : 1);
}

// Layer-2 aggregation over bf16 z (zh): wave per (node, graph); 2 ch/lane. Unroll 8.
__global__ void agg2_kernel(const unsigned short* __restrict__ zh,
                            const int* __restrict__ off_p, const int* __restrict__ cnt_p, const int* __restrict__ list_p,
                            const int* __restrict__ off_n, const int* __restrict__ cnt_n, const int* __restrict__ list_n,
                            float* __restrict__ Ap, float* __restrict__ An, int n) {
  int wid = (blockIdx.x * blockDim.x + threadIdx.x) >> 6;
  int lane = threadIdx.x & 63;
  int v = wid >> 1;
  if (v >= n) return;
  int g = wid & 1;
  const int* off = g ? off_n : off_p;
  const int* cnt = g ? cnt_n : cnt_p;
  const int* lst = g ? list_n : list_p;
  float* A = g ? An : Ap;
  int d = cnt[v], o = off[v];
  float acc0 = 0.f, acc1 = 0.f;
  int i = 0;
  for (; i + 8 <= d; i += 8) {
    int s0 = lst[o + i],     s1 = lst[o + i + 1], s2 = lst[o + i + 2], s3 = lst[o + i + 3];
    int s4 = lst[o + i + 4], s5 = lst[o + i + 5], s6 = lst[o + i + 6], s7 = lst[o + i + 7];
    unsigned u0 = *(const unsigned*)(zh + (size_t)s0 * 128 + lane * 2);
    unsigned u1 = *(const unsigned*)(zh + (size_t)s1 * 128 + lane * 2);
    unsigned u2 = *(const unsigned*)(zh + (size_t)s2 * 128 + lane * 2);
    unsigned u3 = *(const unsigned*)(zh + (size_t)s3 * 128 + lane * 2);
    unsigned u4 = *(const unsigned*)(zh + (size_t)s4 * 128 + lane * 2);
    unsigned u5 = *(const unsigned*)(zh + (size_t)s5 * 128 + lane * 2);
    unsigned u6 = *(const unsigned*)(zh + (size_t)s6 * 128 + lane * 2);
    unsigned u7 = *(const unsigned*)(zh + (size_t)s7 * 128 + lane * 2);
    acc0 += ((bflo(u0) + bflo(u1)) + (bflo(u2) + bflo(u3))) +
            ((bflo(u4) + bflo(u5)) + (bflo(u6) + bflo(u7)));
    acc1 += ((bfhi(u0) + bfhi(u1)) + (bfhi(u2) + bfhi(u3))) +
            ((bfhi(u4) + bfhi(u5)) + (bfhi(u6) + bfhi(u7)));
  }
  for (; i < d; ++i) {
    unsigned u = *(const unsigned*)(zh + (size_t)lst[o + i] * 128 + lane * 2);
    acc0 += bflo(u);
    acc1 += bfhi(u);
  }
  float inv = 1.f / (float)(d > 0 ? d : 1);
  *(float2*)(A + (size_t)v * 128 + lane * 2) = make_float2(acc0 * inv, acc1 * inv);
}

// zh[:, half*64 + lane] = bf16(relu([M, x] @ W.T + b)). [R6-proven]
__global__ __launch_bounds__(512, 4) void lin1_kernel(
    const float* __restrict__ x, const float* __restrict__ Mp, const float* __restrict__ Mn,
    const float* __restrict__ Wp1, const float* __restrict__ bp1,
    const float* __restrict__ Wn1, const float* __restrict__ bn1,
    unsigned short* __restrict__ zh, int n) {
  __shared__ float Wt[64 * 128];  // 32 KiB, [j][k] with k4 XOR-swizzle
  int half = blockIdx.y;
  const float* W  = half ? Wn1 : Wp1;
  const float* bb = half ? bn1 : bp1;
  const float* M  = half ? Mn : Mp;
  for (int f = threadIdx.x; f < 64 * 128; f += 512) {
    int j = f >> 7, k = f & 127;
    int k4 = k >> 2, kr = k & 3;
    Wt[(j * 32 + (k4 ^ (j & 7))) * 4 + kr] = W[f];  // coalesced global read
  }
  __syncthreads();
  int lane = threadIdx.x & 63;
  float bias = bb[lane];
  int wrow = lane * 32;
  int wsw = lane & 7;
  int gw = blockIdx.x * 8 + (threadIdx.x >> 6);
  int wstride = gridDim.x * 8;
  for (int v0 = gw * 4; v0 < n; v0 += wstride * 4) {
    int vB = (v0 + 1 < n) ? v0 + 1 : v0;
    int vC = (v0 + 2 < n) ? v0 + 2 : v0;
    int vD = (v0 + 3 < n) ? v0 + 3 : v0;
    const float4* mA = (const float4*)(M + (size_t)v0 * 64);
    const float4* mB = (const float4*)(M + (size_t)vB * 64);
    const float4* mC = (const float4*)(M + (size_t)vC * 64);
    const float4* mD = (const float4*)(M + (size_t)vD * 64);
    const float4* xA = (const float4*)(x + (size_t)v0 * 64);
    const float4* xB = (const float4*)(x + (size_t)vB * 64);
    const float4* xC = (const float4*)(x + (size_t)vC * 64);
    const float4* xD = (const float4*)(x + (size_t)vD * 64);
    float aA0 = bias, aA1 = 0.f, aB0 = bias, aB1 = 0.f;
    float aC0 = bias, aC1 = 0.f, aD0 = bias, aD1 = 0.f;
    #pragma unroll 2
    for (int k4 = 0; k4 < 16; ++k4) {
      float4 w4 = *(const float4*)&Wt[(wrow + (k4 ^ wsw)) * 4];
      float4 uA = mA[k4]; float4 uB = mB[k4]; float4 uC = mC[k4]; float4 uD = mD[k4];
      aA0 = fmaf(uA.x, w4.x, aA0); aA1 = fmaf(uA.y, w4.y, aA1);
      aA0 = fmaf(uA.z, w4.z, aA0); aA1 = fmaf(uA.w, w4.w, aA1);
      aB0 = fmaf(uB.x, w4.x, aB0); aB1 = fmaf(uB.y, w4.y, aB1);
      aB0 = fmaf(uB.z, w4.z, aB0); aB1 = fmaf(uB.w, w4.w, aB1);
      aC0 = fmaf(uC.x, w4.x, aC0); aC1 = fmaf(uC.y, w4.y, aC1);
      aC0 = fmaf(uC.z, w4.z, aC0); aC1 = fmaf(uC.w, w4.w, aC1);
      aD0 = fmaf(uD.x, w4.x, aD0); aD1 = fmaf(uD.y, w4.y, aD1);
      aD0 = fmaf(uD.z, w4.z, aD0); aD1 = fmaf(uD.w, w4.w, aD1);
    }
    #pragma unroll 2
    for (int k4 = 16; k4 < 32; ++k4) {
      float4 w4 = *(const float4*)&Wt[(wrow + (k4 ^ wsw)) * 4];
      int kk = k4 - 16;
      float4 uA = xA[kk]; float4 uB = xB[kk]; float4 uC = xC[kk]; float4 uD = xD[kk];
      aA0 = fmaf(uA.x, w4.x, aA0); aA1 = fmaf(uA.y, w4.y, aA1);
      aA0 = fmaf(uA.z, w4.z, aA0); aA1 = fmaf(uA.w, w4.w, aA1);
      aB0 = fmaf(uB.x, w4.x, aB0); aB1 = fmaf(uB.y, w4.y, aB1);
      aB0 = fmaf(uB.z, w4.z, aB0); aB1 = fmaf(uB.w, w4.w, aB1);
      aC0 = fmaf(uC.x, w4.x, aC0); aC1 = fmaf(uC.y, w4.y, aC1);
      aC0 = fmaf(uC.z, w4.z, aC0); aC1 = fmaf(uC.w, w4.w, aC1);
      aD0 = fmaf(uD.x, w4.x, aD0); aD1 = fmaf(uD.y, w4.y, aD1);
      aD0 = fmaf(uD.z, w4.z, aD0); aD1 = fmaf(uD.w, w4.w, aD1);
    }
    size_t col = (size_t)half * 64 + lane;
    zh[(size_t)v0 * 128 + col] = f2bf(fmaxf(aA0 + aA1, 0.f));
    if (v0 + 1 < n) zh[(size_t)(v0 + 1) * 128 + col] = f2bf(fmaxf(aB0 + aB1, 0.f));
    if (v0 + 2 < n) zh[(size_t)(v0 + 2) * 128 + col] = f2bf(fmaxf(aC0 + aC1, 0.f));
    if (v0 + 3 < n) zh[(size_t)(v0 + 3) * 128 + col] = f2bf(fmaxf(aD0 + aD1, 0.f));
  }
}

// out[:, half*64+lane] = relu([A1, A2, Zr] @ W.T + b); A f32, Zr bf16. [R6-proven]
__global__ __launch_bounds__(512, 4) void lin2_kernel(
    const unsigned short* __restrict__ zh, const float* __restrict__ Ap, const float* __restrict__ An,
    const float* __restrict__ Wp2, const float* __restrict__ bp2,
    const float* __restrict__ Wn2, const float* __restrict__ bn2,
    float* __restrict__ out, int n) {
  __shared__ float Wt[64 * 192];  // 48 KiB
  int half = blockIdx.y;
  const float* W  = half ? Wn2 : Wp2;
  const float* bb = half ? bn2 : bp2;
  for (int f = threadIdx.x; f < 64 * 192; f += 512) {
    int j = f / 192, k = f - j * 192;
    int k4 = k >> 2, kr = k & 3;
    Wt[(j * 48 + (k4 ^ (j & 7))) * 4 + kr] = W[f];  // coalesced global read
  }
  __syncthreads();
  int lane = threadIdx.x & 63;
  float bias = bb[lane];
  int wrow = lane * 48;
  int wsw = lane & 7;
  int gw = blockIdx.x * 8 + (threadIdx.x >> 6);
  int wstride = gridDim.x * 8;
  size_t a1off = half ? 64 : 0;
  size_t a2off = half ? 0 : 64;
  size_t zoff  = half ? 64 : 0;
  for (int v0 = gw * 4; v0 < n; v0 += wstride * 4) {
    int vB = (v0 + 1 < n) ? v0 + 1 : v0;
    int vC = (v0 + 2 < n) ? v0 + 2 : v0;
    int vD = (v0 + 3 < n) ? v0 + 3 : v0;
    const float4* p1A = (const float4*)(Ap + (size_t)v0 * 128 + a1off);
    const float4* p1B = (const float4*)(Ap + (size_t)vB * 128 + a1off);
    const float4* p1C = (const float4*)(Ap + (size_t)vC * 128 + a1off);
    const float4* p1D = (const float4*)(Ap + (size_t)vD * 128 + a1off);
    float aA0 = bias, aA1 = 0.f, aB0 = bias, aB1 = 0.f;
    float aC0 = bias, aC1 = 0.f, aD0 = bias, aD1 = 0.f;
    #pragma unroll 2
    for (int k4 = 0; k4 < 16; ++k4) {
      float4 w4 = *(const float4*)&Wt[(wrow + (k4 ^ wsw)) * 4];
      float4 uA = p1A[k4]; float4 uB = p1B[k4]; float4 uC = p1C[k4]; float4 uD = p1D[k4];
      aA0 = fmaf(uA.x, w4.x, aA0); aA1 = fmaf(uA.y, w4.y, aA1);
      aA0 = fmaf(uA.z, w4.z, aA0); aA1 = fmaf(uA.w, w4.w, aA1);
      aB0 = fmaf(uB.x, w4.x, aB0); aB1 = fmaf(uB.y, w4.y, aB1);
      aB0 = fmaf(uB.z, w4.z, aB0); aB1 = fmaf(uB.w, w4.w, aB1);
      aC0 = fmaf(uC.x, w4.x, aC0); aC1 = fmaf(uC.y, w4.y, aC1);
      aC0 = fmaf(uC.z, w4.z, aC0); aC1 = fmaf(uC.w, w4.w, aC1);
      aD0 = fmaf(uD.x, w4.x, aD0); aD1 = fmaf(uD.y, w4.y, aD1);
      aD0 = fmaf(uD.z, w4.z, aD0); aD1 = fmaf(uD.w, w4.w, aD1);
    }
    const float4* p2A = (const float4*)(An + (size_t)v0 * 128 + a2off);
    const float4* p2B = (const float4*)(An + (size_t)vB * 128 + a2off);
    const float4* p2C = (const float4*)(An + (size_t)vC * 128 + a2off);
    const float4* p2D = (const float4*)(An + (size_t)vD * 128 + a2off);
    #pragma unroll 2
    for (int k4 = 16; k4 < 32; ++k4) {
      float4 w4 = *(const float4*)&Wt[(wrow + (k4 ^ wsw)) * 4];
      int kk = k4 - 16;
      float4 uA = p2A[kk]; float4 uB = p2B[kk]; float4 uC = p2C[kk]; float4 uD = p2D[kk];
      aA0 = fmaf(uA.x, w4.x, aA0); aA1 = fmaf(uA.y, w4.y, aA1);
      aA0 = fmaf(uA.z, w4.z, aA0); aA1 = fmaf(uA.w, w4.w, aA1);
      aB0 = fmaf(uB.x, w4.x, aB0); aB1 = fmaf(uB.y, w4.y, aB1);
      aB0 = fmaf(uB.z, w4.z, aB0); aB1 = fmaf(uB.w, w4.w, aB1);
      aC0 = fmaf(uC.x, w4.x, aC0); aC1 = fmaf(uC.y, w4.y, aC1);
      aC0 = fmaf(uC.z, w4.z, aC0); aC1 = fmaf(uC.w, w4.w, aC1);
      aD0 = fmaf(uD.x, w4.x, aD0); aD1 = fmaf(uD.y, w4.y, aD1);
      aD0 = fmaf(uD.z, w4.z, aD0); aD1 = fmaf(uD.w, w4.w, aD1);
    }
    const unsigned short* zA = zh + (size_t)v0 * 128 + zoff;
    const unsigned short* zB = zh + (size_t)vB * 128 + zoff;
    const unsigned short* zC = zh + (size_t)vC * 128 + zoff;
    const unsigned short* zD = zh + (size_t)vD * 128 + zoff;
    #pragma unroll 2
    for (int k4 = 32; k4 < 48; ++k4) {
      float4 w4 = *(const float4*)&Wt[(wrow + (k4 ^ wsw)) * 4];
      int kk = k4 - 32;
      uint2 qA = *(const uint2*)(zA + (kk << 2));
      uint2 qB = *(const uint2*)(zB + (kk << 2));
      uint2 qC = *(const uint2*)(zC + (kk << 2));
      uint2 qD = *(const uint2*)(zD + (kk << 2));
      aA0 = fmaf(bflo(qA.x), w4.x, aA0); aA1 = fmaf(bfhi(qA.x), w4.y, aA1);
      aA0 = fmaf(bflo(qA.y), w4.z, aA0); aA1 = fmaf(bfhi(qA.y), w4.w, aA1);
      aB0 = fmaf(bflo(qB.x), w4.x, aB0); aB1 = fmaf(bfhi(qB.x), w4.y, aB1);
      aB0 = fmaf(bflo(qB.y), w4.z, aB0); aB1 = fmaf(bfhi(qB.y), w4.w, aB1);
      aC0 = fmaf(bflo(qC.x), w4.x, aC0); aC1 = fmaf(bfhi(qC.x), w4.y, aC1);
      aC0 = fmaf(bflo(qC.y), w4.z, aC0); aC1 = fmaf(bfhi(qC.y), w4.w, aC1);
      aD0 = fmaf(bflo(qD.x), w4.x, aD0); aD1 = fmaf(bfhi(qD.x), w4.y, aD1);
      aD0 = fmaf(bflo(qD.y), w4.z, aD0); aD1 = fmaf(bfhi(qD.y), w4.w, aD1);
    }
    size_t col = (size_t)half * 64 + lane;
    out[(size_t)v0 * 128 + col] = fmaxf(aA0 + aA1, 0.f);
    if (v0 + 1 < n) out[(size_t)(v0 + 1) * 128 + col] = fmaxf(aB0 + aB1, 0.f);
    if (v0 + 2 < n) out[(size_t)(v0 + 2) * 128 + col] = fmaxf(aC0 + aC1, 0.f);
    if (v0 + 3 < n) out[(size_t)(v0 + 3) * 128 + col] = fmaxf(aD0 + aD1, 0.f);
  }
}

extern "C" void kernel_launch(void* const* d_in, const int* in_sizes, int n_in,
                              void* d_out, int out_size, void* d_ws, size_t ws_size,
                              hipStream_t stream) {
  const float* x   = (const float*)d_in[0];
  const int*   pei = (const int*)d_in[1];
  const int*   nei = (const int*)d_in[2];
  const float* Wp1 = (const float*)d_in[3];
  const float* bp1 = (const float*)d_in[4];
  const float* Wn1 = (const float*)d_in[5];
  const float* bn1 = (const float*)d_in[6];
  const float* Wp2 = (const float*)d_in[7];
  const float* bp2 = (const float*)d_in[8];
  const float* Wn2 = (const float*)d_in[9];
  const float* bn2 = (const float*)d_in[10];
  float* out = (float*)d_out;

  const int n = in_sizes[0] / 64;   // 100000
  const int e = in_sizes[1] / 2;    // 1600000

  char* w = (char*)d_ws;
  size_t off = 0;
  auto take = [&](size_t bytes) -> void* {
    void* p = (void*)(w + off);
    off += (bytes + 255) & ~(size_t)255;
    return p;
  };
  int* cnt_p  = (int*)take((size_t)n * 4);
  int* cnt_n  = (int*)take((size_t)n * 4);
  int* tots   = (int*)take(8);
  int* off_p  = (int*)take((size_t)n * 4);
  int* off_n  = (int*)take((size_t)n * 4);
  int* slot_p = (int*)take((size_t)e * 4);
  int* slot_n = (int*)take((size_t)e * 4);
  int* list_p = (int*)take((size_t)e * 4);
  int* list_n = (int*)take((size_t)e * 4);
  float* Mp = (float*)take((size_t)n * 64 * 4);   // 256B-multiple => Mn contiguous
  float* Mn = (float*)take((size_t)n * 64 * 4);
  unsigned short* zh = (unsigned short*)take((size_t)n * 128 * 2);
  float* An = (float*)take((size_t)n * 128 * 4);
  float* Ap = Mp;  // alias: Mp/Mn dead after lin1; Ap spans both (n*128 floats)

  hipMemsetAsync(cnt_p, 0, (size_t)n * 4, stream);
  hipMemsetAsync(cnt_n, 0, (size_t)n * 4, stream);
  hipMemsetAsync(tots, 0, 8, stream);

  int blkE = (2 * e + 255) / 256;
  count_kernel<<<blkE, 256, 0, stream>>>(pei, nei, cnt_p, cnt_n, slot_p, slot_n, e);
  alloc_kernel<<<(n + 255) / 256, 256, 0, stream>>>(cnt_p, cnt_n, off_p, off_n, tots, n);
  fill_kernel<<<2048, 256, 0, stream>>>(pei, nei, off_p, off_n, slot_p, slot_n,
                                        list_p, list_n, e, n);

  // layer 1
  agg1_kernel<<<(2 * n * 64 + 255) / 256, 256, 0, stream>>>(
      x, off_p, cnt_p, list_p, off_n, cnt_n, list_n, Mp, Mn, n);
  dim3 gl(768, 2);
  lin1_kernel<<<gl, 512, 0, stream>>>(x, Mp, Mn, Wp1, bp1, Wn1, bn1, zh, n);

  // layer 2
  agg2_kernel<<<(2 * n * 64 + 255) / 256, 256, 0, stream>>>(
      zh, off_p, cnt_p, list_p, off_n, cnt_n, list_n, Ap, An, n);
  lin2_kernel<<<gl, 512, 0, stream>>>(zh, Ap, An, Wp2, bp2, Wn2, bn2, out, n);
}

// Round 8
// 705.046 us; speedup vs baseline: 8.5939x; 1.5111x over previous
//
#include <hip/hip_runtime.h>

// SignedGCN on MI355X. R8: MFMA linears (bf16, LDS-free), bf16 everywhere on
// the gather/matmul path. CSR build (count/alloc/fill) = R7-proven.

typedef unsigned short u16;
typedef __attribute__((ext_vector_type(8))) short s8v;    // 8 bf16 = 4 VGPRs
typedef __attribute__((ext_vector_type(4))) float f32x4;  // MFMA accumulator

__device__ __forceinline__ float bf2f(u16 u) { return __uint_as_float(((unsigned)u) << 16); }
__device__ __forceinline__ float bflo(unsigned u) { return __uint_as_float(u << 16); }
__device__ __forceinline__ float bfhi(unsigned u) { return __uint_as_float(u & 0xFFFF0000u); }
__device__ __forceinline__ u16 f2bf(float f) {
  unsigned u = __float_as_uint(f);
  return (u16)((u + 0x7FFFu + ((u >> 16) & 1u)) >> 16);
}

// ---------------- CSR build (R7-proven) ----------------
__global__ void count_kernel(const int* __restrict__ pei, const int* __restrict__ nei,
                             int* __restrict__ cnt_p, int* __restrict__ cnt_n,
                             int* __restrict__ slot_p, int* __restrict__ slot_n, int e) {
  int i = blockIdx.x * blockDim.x + threadIdx.x;
  if (i < e) {
    slot_p[i] = atomicAdd(&cnt_p[pei[e + i]], 1);
  } else if (i < 2 * e) {
    int j = i - e;
    slot_n[j] = atomicAdd(&cnt_n[nei[e + j]], 1);
  }
}

__global__ void alloc_kernel(const int* __restrict__ cnt_p, const int* __restrict__ cnt_n,
                             int* __restrict__ off_p, int* __restrict__ off_n,
                             int* __restrict__ tots, int n) {
  int v = blockIdx.x * blockDim.x + threadIdx.x;
  int lane = threadIdx.x & 63;
  int vp = (v < n) ? cnt_p[v] : 0;
  int vn = (v < n) ? cnt_n[v] : 0;
  int sp = vp, sn = vn;
  #pragma unroll
  for (int d = 1; d < 64; d <<= 1) {
    int tp = __shfl_up(sp, d);
    int tn = __shfl_up(sn, d);
    if (lane >= d) { sp += tp; sn += tn; }
  }
  int basep = 0, basen = 0;
  if (lane == 63) {
    basep = atomicAdd(&tots[0], sp);
    basen = atomicAdd(&tots[1], sn);
  }
  basep = __shfl(basep, 63);
  basen = __shfl(basen, 63);
  if (v < n) {
    off_p[v] = basep + sp - vp;
    off_n[v] = basen + sn - vn;
  }
}

__global__ void fill_kernel(const int* __restrict__ pei, const int* __restrict__ nei,
                            const int* __restrict__ off_p, const int* __restrict__ off_n,
                            const int* __restrict__ slot_p, const int* __restrict__ slot_n,
                            int* __restrict__ list_p, int* __restrict__ list_n,
                            int e, int n) {
  int stride = gridDim.x * blockDim.x;
  int nq = (n + 3) >> 2;
  for (int pass = 0; pass < 4; ++pass) {
    int lo = pass * nq;
    int hi = lo + nq; if (hi > n) hi = n;
    for (int i = blockIdx.x * blockDim.x + threadIdx.x; i < 2 * e; i += stride) {
      if (i < e) {
        int dst = pei[e + i];
        if (dst >= lo && dst < hi) list_p[off_p[dst] + slot_p[i]] = pei[i];
      } else {
        int j = i - e;
        int dst = nei[e + j];
        if (dst >= lo && dst < hi) list_n[off_n[dst] + slot_n[j]] = nei[j];
      }
    }
  }
}

// ---------------- bf16 converts ----------------
__global__ void convx_kernel(const float* __restrict__ x, u16* __restrict__ xh, int total4) {
  int stride = gridDim.x * blockDim.x;
  for (int i = blockIdx.x * blockDim.x + threadIdx.x; i < total4; i += stride) {
    float4 v = ((const float4*)x)[i];
    unsigned lo = (unsigned)f2bf(v.x) | ((unsigned)f2bf(v.y) << 16);
    unsigned hi = (unsigned)f2bf(v.z) | ((unsigned)f2bf(v.w) << 16);
    ((uint2*)xh)[i] = make_uint2(lo, hi);
  }
}

__global__ void convw_kernel(const float* __restrict__ Wp1, const float* __restrict__ Wn1,
                             const float* __restrict__ Wp2, const float* __restrict__ Wn2,
                             u16* __restrict__ wh1, u16* __restrict__ wh2) {
  int stride = gridDim.x * blockDim.x;
  const int total = 16384 + 24576;
  for (int i = blockIdx.x * blockDim.x + threadIdx.x; i < total; i += stride) {
    if (i < 8192)        wh1[i] = f2bf(Wp1[i]);
    else if (i < 16384)  wh1[i] = f2bf(Wn1[i - 8192]);
    else if (i < 28672)  wh2[i - 16384] = f2bf(Wp2[i - 16384]);
    else                 wh2[i - 16384] = f2bf(Wn2[i - 28672]);
  }
}

// ---------------- aggregation (bf16 in/out) ----------------
// agg1: wave per (node, graph); lane = channel (64). Gathers bf16 x rows (128B).
__global__ void agg1_kernel(const u16* __restrict__ xh,
                            const int* __restrict__ off_p, const int* __restrict__ cnt_p, const int* __restrict__ list_p,
                            const int* __restrict__ off_n, const int* __restrict__ cnt_n, const int* __restrict__ list_n,
                            u16* __restrict__ Mhp, u16* __restrict__ Mhn, int n) {
  int wid = (blockIdx.x * blockDim.x + threadIdx.x) >> 6;
  int lane = threadIdx.x & 63;
  int v = wid >> 1;
  if (v >= n) return;
  int g = wid & 1;
  const int* off = g ? off_n : off_p;
  const int* cnt = g ? cnt_n : cnt_p;
  const int* lst = g ? list_n : list_p;
  u16* M = g ? Mhn : Mhp;
  int d = cnt[v], o = off[v];
  float acc = 0.f;
  int i = 0;
  for (; i + 8 <= d; i += 8) {
    int s0 = lst[o + i],     s1 = lst[o + i + 1], s2 = lst[o + i + 2], s3 = lst[o + i + 3];
    int s4 = lst[o + i + 4], s5 = lst[o + i + 5], s6 = lst[o + i + 6], s7 = lst[o + i + 7];
    float r0 = bf2f(xh[(size_t)s0 * 64 + lane]);
    float r1 = bf2f(xh[(size_t)s1 * 64 + lane]);
    float r2 = bf2f(xh[(size_t)s2 * 64 + lane]);
    float r3 = bf2f(xh[(size_t)s3 * 64 + lane]);
    float r4 = bf2f(xh[(size_t)s4 * 64 + lane]);
    float r5 = bf2f(xh[(size_t)s5 * 64 + lane]);
    float r6 = bf2f(xh[(size_t)s6 * 64 + lane]);
    float r7 = bf2f(xh[(size_t)s7 * 64 + lane]);
    acc += ((r0 + r1) + (r2 + r3)) + ((r4 + r5) + (r6 + r7));
  }
  for (; i < d; ++i) acc += bf2f(xh[(size_t)lst[o + i] * 64 + lane]);
  M[(size_t)v * 64 + lane] = f2bf(acc / (float)(d > 0 ? d : 1));
}

// agg2: wave per (node, graph); lane = 2 channels of 128. bf16 out (packed u32).
__global__ void agg2_kernel(const u16* __restrict__ zh,
                            const int* __restrict__ off_p, const int* __restrict__ cnt_p, const int* __restrict__ list_p,
                            const int* __restrict__ off_n, const int* __restrict__ cnt_n, const int* __restrict__ list_n,
                            u16* __restrict__ Ahp, u16* __restrict__ Ahn, int n) {
  int wid = (blockIdx.x * blockDim.x + threadIdx.x) >> 6;
  int lane = threadIdx.x & 63;
  int v = wid >> 1;
  if (v >= n) return;
  int g = wid & 1;
  const int* off = g ? off_n : off_p;
  const int* cnt = g ? cnt_n : cnt_p;
  const int* lst = g ? list_n : list_p;
  u16* A = g ? Ahn : Ahp;
  int d = cnt[v], o = off[v];
  float acc0 = 0.f, acc1 = 0.f;
  int i = 0;
  for (; i + 8 <= d; i += 8) {
    int s0 = lst[o + i],     s1 = lst[o + i + 1], s2 = lst[o + i + 2], s3 = lst[o + i + 3];
    int s4 = lst[o + i + 4], s5 = lst[o + i + 5], s6 = lst[o + i + 6], s7 = lst[o + i + 7];
    unsigned u0 = *(const unsigned*)(zh + (size_t)s0 * 128 + lane * 2);
    unsigned u1 = *(const unsigned*)(zh + (size_t)s1 * 128 + lane * 2);
    unsigned u2 = *(const unsigned*)(zh + (size_t)s2 * 128 + lane * 2);
    unsigned u3 = *(const unsigned*)(zh + (size_t)s3 * 128 + lane * 2);
    unsigned u4 = *(const unsigned*)(zh + (size_t)s4 * 128 + lane * 2);
    unsigned u5 = *(const unsigned*)(zh + (size_t)s5 * 128 + lane * 2);
    unsigned u6 = *(const unsigned*)(zh + (size_t)s6 * 128 + lane * 2);
    unsigned u7 = *(const unsigned*)(zh + (size_t)s7 * 128 + lane * 2);
    acc0 += ((bflo(u0) + bflo(u1)) + (bflo(u2) + bflo(u3))) +
            ((bflo(u4) + bflo(u5)) + (bflo(u6) + bflo(u7)));
    acc1 += ((bfhi(u0) + bfhi(u1)) + (bfhi(u2) + bfhi(u3))) +
            ((bfhi(u4) + bfhi(u5)) + (bfhi(u6) + bfhi(u7)));
  }
  for (; i < d; ++i) {
    unsigned u = *(const unsigned*)(zh + (size_t)lst[o + i] * 128 + lane * 2);
    acc0 += bflo(u);
    acc1 += bfhi(u);
  }
  float inv = 1.f / (float)(d > 0 ? d : 1);
  unsigned pk = (unsigned)f2bf(acc0 * inv) | ((unsigned)f2bf(acc1 * inv) << 16);
  ((unsigned*)(A + (size_t)v * 128))[lane] = pk;
}

// ---------------- MFMA linears (LDS-free) ----------------
// Wave computes 16 rows x 64 outcols. A-frag: lane l -> row=l&15, k=(l>>4)*8+j.
// B-frag: lane l -> col=l&15, k=(l>>4)*8+j (W[col][k] row-major). C/D: col=lane&15,
// row=(lane>>4)*4+reg [m89-verified].
__global__ void lin1_mfma(const u16* __restrict__ xh, const u16* __restrict__ Mhp,
                          const u16* __restrict__ Mhn, const u16* __restrict__ wh1,
                          const float* __restrict__ bp1, const float* __restrict__ bn1,
                          u16* __restrict__ zh, int n) {
  int half = blockIdx.y;
  const u16* W = wh1 + (size_t)half * 64 * 128;
  const float* bb = half ? bn1 : bp1;
  const u16* Mh = half ? Mhn : Mhp;
  int l = threadIdx.x & 63;
  int r16 = l & 15, q = l >> 4;
  float b0 = bb[r16], b1 = bb[16 + r16], b2 = bb[32 + r16], b3 = bb[48 + r16];
  int wv = blockIdx.x * 4 + (threadIdx.x >> 6);
  int wstride = gridDim.x * 4;
  int ntiles = (n + 15) >> 4;
  for (int t = wv; t < ntiles; t += wstride) {
    int row0 = t << 4;
    int row = row0 + r16;
    f32x4 acc0 = {0.f, 0.f, 0.f, 0.f};
    f32x4 acc1 = {0.f, 0.f, 0.f, 0.f};
    f32x4 acc2 = {0.f, 0.f, 0.f, 0.f};
    f32x4 acc3 = {0.f, 0.f, 0.f, 0.f};
    #pragma unroll
    for (int kk = 0; kk < 4; ++kk) {
      const u16* asrc = (kk < 2)
          ? (Mh + (size_t)row * 64 + kk * 32 + q * 8)
          : (xh + (size_t)row * 64 + (kk - 2) * 32 + q * 8);
      s8v af = *(const s8v*)asrc;
      const u16* wb = W + kk * 32 + q * 8;
      s8v bf0 = *(const s8v*)(wb + (size_t)(r16) * 128);
      s8v bf1 = *(const s8v*)(wb + (size_t)(16 + r16) * 128);
      s8v bf2 = *(const s8v*)(wb + (size_t)(32 + r16) * 128);
      s8v bf3 = *(const s8v*)(wb + (size_t)(48 + r16) * 128);
      acc0 = __builtin_amdgcn_mfma_f32_16x16x32_bf16(af, bf0, acc0, 0, 0, 0);
      acc1 = __builtin_amdgcn_mfma_f32_16x16x32_bf16(af, bf1, acc1, 0, 0, 0);
      acc2 = __builtin_amdgcn_mfma_f32_16x16x32_bf16(af, bf2, acc2, 0, 0, 0);
      acc3 = __builtin_amdgcn_mfma_f32_16x16x32_bf16(af, bf3, acc3, 0, 0, 0);
    }
    #pragma unroll
    for (int r = 0; r < 4; ++r) {
      size_t base = (size_t)(row0 + q * 4 + r) * 128 + half * 64;
      zh[base + r16]      = f2bf(fmaxf(acc0[r] + b0, 0.f));
      zh[base + 16 + r16] = f2bf(fmaxf(acc1[r] + b1, 0.f));
      zh[base + 32 + r16] = f2bf(fmaxf(acc2[r] + b2, 0.f));
      zh[base + 48 + r16] = f2bf(fmaxf(acc3[r] + b3, 0.f));
    }
  }
}

__global__ void lin2_mfma(const u16* __restrict__ zh, const u16* __restrict__ Ahp,
                          const u16* __restrict__ Ahn, const u16* __restrict__ wh2,
                          const float* __restrict__ bp2, const float* __restrict__ bn2,
                          float* __restrict__ out, int n) {
  int half = blockIdx.y;
  const u16* W = wh2 + (size_t)half * 64 * 192;
  const float* bb = half ? bn2 : bp2;
  int a1off = half ? 64 : 0;
  int a2off = half ? 0 : 64;
  int zoff  = half ? 64 : 0;
  int l = threadIdx.x & 63;
  int r16 = l & 15, q = l >> 4;
  float b0 = bb[r16], b1 = bb[16 + r16], b2 = bb[32 + r16], b3 = bb[48 + r16];
  int wv = blockIdx.x * 4 + (threadIdx.x >> 6);
  int wstride = gridDim.x * 4;
  int ntiles = (n + 15) >> 4;
  for (int t = wv; t < ntiles; t += wstride) {
    int row0 = t << 4;
    int row = row0 + r16;
    f32x4 acc0 = {0.f, 0.f, 0.f, 0.f};
    f32x4 acc1 = {0.f, 0.f, 0.f, 0.f};
    f32x4 acc2 = {0.f, 0.f, 0.f, 0.f};
    f32x4 acc3 = {0.f, 0.f, 0.f, 0.f};
    #pragma unroll
    for (int kk = 0; kk < 6; ++kk) {
      const u16* asrc;
      if (kk < 2)       asrc = Ahp + (size_t)row * 128 + a1off + kk * 32 + q * 8;
      else if (kk < 4)  asrc = Ahn + (size_t)row * 128 + a2off + (kk - 2) * 32 + q * 8;
      else              asrc = zh  + (size_t)row * 128 + zoff  + (kk - 4) * 32 + q * 8;
      s8v af = *(const s8v*)asrc;
      const u16* wb = W + kk * 32 + q * 8;
      s8v bf0 = *(const s8v*)(wb + (size_t)(r16) * 192);
      s8v bf1 = *(const s8v*)(wb + (size_t)(16 + r16) * 192);
      s8v bf2 = *(const s8v*)(wb + (size_t)(32 + r16) * 192);
      s8v bf3 = *(const s8v*)(wb + (size_t)(48 + r16) * 192);
      acc0 = __builtin_amdgcn_mfma_f32_16x16x32_bf16(af, bf0, acc0, 0, 0, 0);
      acc1 = __builtin_amdgcn_mfma_f32_16x16x32_bf16(af, bf1, acc1, 0, 0, 0);
      acc2 = __builtin_amdgcn_mfma_f32_16x16x32_bf16(af, bf2, acc2, 0, 0, 0);
      acc3 = __builtin_amdgcn_mfma_f32_16x16x32_bf16(af, bf3, acc3, 0, 0, 0);
    }
    #pragma unroll
    for (int r = 0; r < 4; ++r) {
      size_t base = (size_t)(row0 + q * 4 + r) * 128 + half * 64;
      out[base + r16]      = fmaxf(acc0[r] + b0, 0.f);
      out[base + 16 + r16] = fmaxf(acc1[r] + b1, 0.f);
      out[base + 32 + r16] = fmaxf(acc2[r] + b2, 0.f);
      out[base + 48 + r16] = fmaxf(acc3[r] + b3, 0.f);
    }
  }
}

extern "C" void kernel_launch(void* const* d_in, const int* in_sizes, int n_in,
                              void* d_out, int out_size, void* d_ws, size_t ws_size,
                              hipStream_t stream) {
  const float* x   = (const float*)d_in[0];
  const int*   pei = (const int*)d_in[1];
  const int*   nei = (const int*)d_in[2];
  const float* Wp1 = (const float*)d_in[3];
  const float* bp1 = (const float*)d_in[4];
  const float* Wn1 = (const float*)d_in[5];
  const float* bn1 = (const float*)d_in[6];
  const float* Wp2 = (const float*)d_in[7];
  const float* bp2 = (const float*)d_in[8];
  const float* Wn2 = (const float*)d_in[9];
  const float* bn2 = (const float*)d_in[10];
  float* out = (float*)d_out;

  const int n = in_sizes[0] / 64;   // 100000
  const int e = in_sizes[1] / 2;    // 1600000

  char* w = (char*)d_ws;
  size_t off = 0;
  auto take = [&](size_t bytes) -> void* {
    void* p = (void*)(w + off);
    off += (bytes + 255) & ~(size_t)255;
    return p;
  };
  int* cnt_p  = (int*)take((size_t)n * 4);
  int* cnt_n  = (int*)take((size_t)n * 4);
  int* tots   = (int*)take(8);
  int* off_p  = (int*)take((size_t)n * 4);
  int* off_n  = (int*)take((size_t)n * 4);
  int* slot_p = (int*)take((size_t)e * 4);
  int* slot_n = (int*)take((size_t)e * 4);
  int* list_p = (int*)take((size_t)e * 4);
  int* list_n = (int*)take((size_t)e * 4);
  u16* xh  = (u16*)take((size_t)n * 64 * 2);
  u16* Mhp = (u16*)take((size_t)n * 64 * 2);
  u16* Mhn = (u16*)take((size_t)n * 64 * 2);
  u16* zh  = (u16*)take((size_t)n * 128 * 2);
  u16* Ahp = (u16*)take((size_t)n * 128 * 2);
  u16* Ahn = (u16*)take((size_t)n * 128 * 2);
  u16* wh1 = (u16*)take(2 * 64 * 128 * 2);
  u16* wh2 = (u16*)take(2 * 64 * 192 * 2);

  hipMemsetAsync(cnt_p, 0, (size_t)n * 4, stream);
  hipMemsetAsync(cnt_n, 0, (size_t)n * 4, stream);
  hipMemsetAsync(tots, 0, 8, stream);

  int blkE = (2 * e + 255) / 256;
  count_kernel<<<blkE, 256, 0, stream>>>(pei, nei, cnt_p, cnt_n, slot_p, slot_n, e);
  alloc_kernel<<<(n + 255) / 256, 256, 0, stream>>>(cnt_p, cnt_n, off_p, off_n, tots, n);
  fill_kernel<<<2048, 256, 0, stream>>>(pei, nei, off_p, off_n, slot_p, slot_n,
                                        list_p, list_n, e, n);

  convx_kernel<<<(n * 16 + 255) / 256, 256, 0, stream>>>(x, xh, n * 16);
  convw_kernel<<<160, 256, 0, stream>>>(Wp1, Wn1, Wp2, Wn2, wh1, wh2);

  // layer 1
  agg1_kernel<<<(2 * n * 64 + 255) / 256, 256, 0, stream>>>(
      xh, off_p, cnt_p, list_p, off_n, cnt_n, list_n, Mhp, Mhn, n);
  dim3 gl((n / 64) + 1, 2);   // 1563 x 2, 4 waves/block, 16-row tile per wave
  lin1_mfma<<<gl, 256, 0, stream>>>(xh, Mhp, Mhn, wh1, bp1, bn1, zh, n);

  // layer 2
  agg2_kernel<<<(2 * n * 64 + 255) / 256, 256, 0, stream>>>(
      zh, off_p, cnt_p, list_p, off_n, cnt_n, list_n, Ahp, Ahn, n);
  lin2_mfma<<<gl, 256, 0, stream>>>(zh, Ahp, Ahn, wh2, bp2, bn2, out, n);
}